// Round 1
// baseline (543.269 us; speedup 1.0000x reference)
//
#include <hip/hip_runtime.h>

#define CC 128
#define NSP 16384              // 128*128 spatial
#define NFULL (CC * NSP)

// ---------------------------------------------------------------------------
// K1: per batch b in [0,8): M[b][i][j] = sum_n Xt[i,n]*Xs[j,n]
//     plus row sums rt[b][i] = sum_n Xt[i,n], rs[b][j] = sum_n Xs[j,n]
// grid (64 chunks of 256 n, 8 batches), block 256. fp32 VALU, atomic reduce.
// ---------------------------------------------------------------------------
__global__ __launch_bounds__(256) void k1_gram(const float* __restrict__ x,
    float* __restrict__ M, float* __restrict__ rs, float* __restrict__ rt) {
  const int b = blockIdx.y;
  const int n0 = blockIdx.x * 256;
  const float* Xs = x + (size_t)b * NFULL;
  const float* Xt = x + (size_t)(b + 8) * NFULL;
  __shared__ float At[64][132];   // [n][i]  (transposed tile of Xt)
  __shared__ float As[64][132];   // [n][j]
  const int t = threadIdx.x;
  const int ti8 = (t >> 4) * 8;
  const int tj8 = (t & 15) * 8;
  float acc[8][8];
#pragma unroll
  for (int i = 0; i < 8; ++i)
#pragma unroll
    for (int j = 0; j < 8; ++j) acc[i][j] = 0.f;
  float rsum = 0.f;

  for (int sub = 0; sub < 4; ++sub) {
    const int ns = n0 + sub * 64;
    __syncthreads();
#pragma unroll
    for (int p = 0; p < 8; ++p) {
      int f = p * 256 + t;
      int row = f >> 4;
      int nc = (f & 15) * 4;
      float4 vt = *(const float4*)(Xt + (size_t)row * NSP + ns + nc);
      float4 vs = *(const float4*)(Xs + (size_t)row * NSP + ns + nc);
      At[nc + 0][row] = vt.x; At[nc + 1][row] = vt.y;
      At[nc + 2][row] = vt.z; At[nc + 3][row] = vt.w;
      As[nc + 0][row] = vs.x; As[nc + 1][row] = vs.y;
      As[nc + 2][row] = vs.z; As[nc + 3][row] = vs.w;
    }
    __syncthreads();
    // row sums: waves 0,1 -> Xt rows, waves 2,3 -> Xs rows
    if (t < 128) {
      for (int n = 0; n < 64; ++n) rsum += At[n][t];
    } else {
      for (int n = 0; n < 64; ++n) rsum += As[n][t - 128];
    }
#pragma unroll 2
    for (int n = 0; n < 64; ++n) {
      float av[8], bv[8];
      *(float4*)&av[0] = *(const float4*)&At[n][ti8];
      *(float4*)&av[4] = *(const float4*)&At[n][ti8 + 4];
      *(float4*)&bv[0] = *(const float4*)&As[n][tj8];
      *(float4*)&bv[4] = *(const float4*)&As[n][tj8 + 4];
#pragma unroll
      for (int i = 0; i < 8; ++i)
#pragma unroll
        for (int j = 0; j < 8; ++j) acc[i][j] += av[i] * bv[j];
    }
  }
  float* Mb = M + (size_t)b * CC * CC;
#pragma unroll
  for (int i = 0; i < 8; ++i)
#pragma unroll
    for (int j = 0; j < 8; ++j)
      atomicAdd(&Mb[(ti8 + i) * CC + (tj8 + j)], acc[i][j]);
  if (t < 128) atomicAdd(&rt[b * CC + t], rsum);
  else         atomicAdd(&rs[b * CC + (t - 128)], rsum);
}

// ---------------------------------------------------------------------------
// K2a: T1 = Wq*M, T2 = Wq*M^T, us = Wq*rs, ut = Wq*rt.  grid (8 rowgrp, 8 b).
// ---------------------------------------------------------------------------
__global__ __launch_bounds__(256) void k2a(const float* __restrict__ M,
    const float* __restrict__ qw, const float* __restrict__ rs,
    const float* __restrict__ rt, float* __restrict__ T1, float* __restrict__ T2,
    float* __restrict__ us, float* __restrict__ ut) {
  const int b = blockIdx.y;
  const int c0 = blockIdx.x * 16;
  __shared__ float Ml[128][129];
  __shared__ float Wq[16][128];
  const int t = threadIdx.x;
  const float* Mb = M + (size_t)b * CC * CC;
#pragma unroll
  for (int p = 0; p < 16; ++p) {
    int f = p * 256 + t;
    int row = f >> 5;
    int c4 = (f & 31) * 4;
    float4 v = *(const float4*)(Mb + row * CC + c4);
    Ml[row][c4 + 0] = v.x; Ml[row][c4 + 1] = v.y;
    Ml[row][c4 + 2] = v.z; Ml[row][c4 + 3] = v.w;
  }
#pragma unroll
  for (int p = 0; p < 2; ++p) {
    int f = p * 256 + t;
    int row = f >> 5;
    int c4 = (f & 31) * 4;
    *(float4*)&Wq[row][c4] = *(const float4*)(qw + (c0 + row) * CC + c4);
  }
  __syncthreads();
  if (t < 32) {                       // u vectors (bias fix-up terms)
    int c = t & 15;
    const float* r = (t < 16) ? rs : rt;
    float s = 0.f;
    for (int i = 0; i < CC; ++i) s += Wq[c][i] * r[b * CC + i];
    if (t < 16) us[b * CC + c0 + c] = s;
    else        ut[b * CC + c0 + c] = s;
  }
  const int tr = t >> 4;
  const int tj8 = (t & 15) * 8;
  float a1[8], a2[8];
#pragma unroll
  for (int j = 0; j < 8; ++j) { a1[j] = 0.f; a2[j] = 0.f; }
  for (int i = 0; i < CC; ++i) {
    float wq = Wq[tr][i];
#pragma unroll
    for (int j = 0; j < 8; ++j) {
      a1[j] += wq * Ml[i][tj8 + j];        // (Wq M)[c][j]
      a2[j] += wq * Ml[tj8 + j][i];        // (Wq M^T)[c][j]
    }
  }
  float* T1b = T1 + (size_t)b * CC * CC + (size_t)(c0 + tr) * CC;
  float* T2b = T2 + (size_t)b * CC * CC + (size_t)(c0 + tr) * CC;
#pragma unroll
  for (int j = 0; j < 8; ++j) { T1b[tj8 + j] = a1[j]; T2b[tj8 + j] = a2[j]; }
}

// ---------------------------------------------------------------------------
// K2b: G = T*Wk^T + u*bk^T + bq*w^T + N*bq*bk^T, row-softmax -> A.
// which==0: st (T1, ut, w from rs) -> Ast ; which==1: ts (T2, us, w from rt).
// grid (8 rowgrp, 8 b, 2 which).
// ---------------------------------------------------------------------------
__global__ __launch_bounds__(256) void k2b(const float* __restrict__ T1,
    const float* __restrict__ T2, const float* __restrict__ kw,
    const float* __restrict__ qb, const float* __restrict__ kb,
    const float* __restrict__ us, const float* __restrict__ ut,
    const float* __restrict__ rs, const float* __restrict__ rt,
    float* __restrict__ Ast, float* __restrict__ Ats) {
  const int b = blockIdx.y;
  const int c0 = blockIdx.x * 16;
  const int which = blockIdx.z;
  __shared__ float Wk[128][129];
  __shared__ float Tl[16][128];
  __shared__ float wv[128];
  __shared__ float uv[16];
  const int t = threadIdx.x;
  const float* Tm = which ? (T2 + (size_t)b * CC * CC) : (T1 + (size_t)b * CC * CC);
#pragma unroll
  for (int p = 0; p < 16; ++p) {
    int f = p * 256 + t;
    int row = f >> 5;
    int c4 = (f & 31) * 4;
    float4 v = *(const float4*)(kw + row * CC + c4);
    Wk[row][c4 + 0] = v.x; Wk[row][c4 + 1] = v.y;
    Wk[row][c4 + 2] = v.z; Wk[row][c4 + 3] = v.w;
  }
#pragma unroll
  for (int p = 0; p < 2; ++p) {
    int f = p * 256 + t;
    int row = f >> 5;
    int c4 = (f & 31) * 4;
    *(float4*)&Tl[row][c4] = *(const float4*)(Tm + (c0 + row) * CC + c4);
  }
  if (t < 16) uv[t] = (which ? us : ut)[b * CC + c0 + t];
  __syncthreads();
  if (t < 128) {
    const float* r = (which ? rt : rs) + b * CC;
    float s = 0.f;
    for (int j = 0; j < CC; ++j) s += Wk[t][j] * r[j];
    wv[t] = s;
  }
  __syncthreads();
  const int tr = t >> 4;
  const int td8 = (t & 15) * 8;
  const int c = c0 + tr;
  const float bqc = qb[c];
  float g[8];
#pragma unroll
  for (int dd = 0; dd < 8; ++dd) {
    int d = td8 + dd;
    g[dd] = uv[tr] * kb[d] + bqc * wv[d] + 16384.f * bqc * kb[d];
  }
  for (int j = 0; j < CC; ++j) {
    float tv = Tl[tr][j];
#pragma unroll
    for (int dd = 0; dd < 8; ++dd) g[dd] += tv * Wk[td8 + dd][j];
  }
  // row softmax over d (16 lanes x 8 vals per row)
  float m = g[0];
#pragma unroll
  for (int dd = 1; dd < 8; ++dd) m = fmaxf(m, g[dd]);
#pragma unroll
  for (int off = 1; off < 16; off <<= 1) m = fmaxf(m, __shfl_xor(m, off));
  float s = 0.f;
#pragma unroll
  for (int dd = 0; dd < 8; ++dd) { g[dd] = expf(g[dd] - m); s += g[dd]; }
#pragma unroll
  for (int off = 1; off < 16; off <<= 1) s += __shfl_xor(s, off);
  const float inv = 1.f / s;
  float* A = (which ? Ats : Ast) + (size_t)b * CC * CC + (size_t)c * CC;
#pragma unroll
  for (int dd = 0; dd < 8; ++dd) A[td8 + dd] = g[dd] * inv;
}

// ---------------------------------------------------------------------------
// K2c: L = Ast * Ats^T, row-softmax -> Att.  grid (8 rowgrp, 8 b).
// ---------------------------------------------------------------------------
__global__ __launch_bounds__(256) void k2c(const float* __restrict__ Ast,
    const float* __restrict__ Ats, float* __restrict__ Att) {
  const int b = blockIdx.y;
  const int c0 = blockIdx.x * 16;
  __shared__ float Bl[128][129];
  __shared__ float Tl[16][128];
  const int t = threadIdx.x;
  const float* Bb = Ats + (size_t)b * CC * CC;
  const float* Tb = Ast + (size_t)b * CC * CC;
#pragma unroll
  for (int p = 0; p < 16; ++p) {
    int f = p * 256 + t;
    int row = f >> 5;
    int c4 = (f & 31) * 4;
    float4 v = *(const float4*)(Bb + row * CC + c4);
    Bl[row][c4 + 0] = v.x; Bl[row][c4 + 1] = v.y;
    Bl[row][c4 + 2] = v.z; Bl[row][c4 + 3] = v.w;
  }
#pragma unroll
  for (int p = 0; p < 2; ++p) {
    int f = p * 256 + t;
    int row = f >> 5;
    int c4 = (f & 31) * 4;
    *(float4*)&Tl[row][c4] = *(const float4*)(Tb + (c0 + row) * CC + c4);
  }
  __syncthreads();
  const int tr = t >> 4;
  const int td8 = (t & 15) * 8;
  float g[8];
#pragma unroll
  for (int dd = 0; dd < 8; ++dd) g[dd] = 0.f;
  for (int e = 0; e < CC; ++e) {
    float tv = Tl[tr][e];
#pragma unroll
    for (int dd = 0; dd < 8; ++dd) g[dd] += tv * Bl[td8 + dd][e];
  }
  float m = g[0];
#pragma unroll
  for (int dd = 1; dd < 8; ++dd) m = fmaxf(m, g[dd]);
#pragma unroll
  for (int off = 1; off < 16; off <<= 1) m = fmaxf(m, __shfl_xor(m, off));
  float s = 0.f;
#pragma unroll
  for (int dd = 0; dd < 8; ++dd) { g[dd] = expf(g[dd] - m); s += g[dd]; }
#pragma unroll
  for (int off = 1; off < 16; off <<= 1) s += __shfl_xor(s, off);
  const float inv = 1.f / s;
  float* A = Att + (size_t)b * CC * CC + (size_t)(c0 + tr) * CC;
#pragma unroll
  for (int dd = 0; dd < 8; ++dd) A[td8 + dd] = g[dd] * inv;
}

// ---------------------------------------------------------------------------
// K2d: P = Att*Wv, c0 = Att*bv.  grid (8 rowgrp, 8 b).
// ---------------------------------------------------------------------------
__global__ __launch_bounds__(256) void k2d(const float* __restrict__ Att,
    const float* __restrict__ vw, const float* __restrict__ vb,
    float* __restrict__ P, float* __restrict__ c0v) {
  const int b = blockIdx.y;
  const int cr0 = blockIdx.x * 16;
  __shared__ float Wv[128][132];   // [d][i], float4-aligned pad
  __shared__ float Al[16][128];
  const int t = threadIdx.x;
  const float* Ab = Att + (size_t)b * CC * CC;
#pragma unroll
  for (int p = 0; p < 16; ++p) {
    int f = p * 256 + t;
    int row = f >> 5;
    int c4 = (f & 31) * 4;
    *(float4*)&Wv[row][c4] = *(const float4*)(vw + row * CC + c4);
  }
#pragma unroll
  for (int p = 0; p < 2; ++p) {
    int f = p * 256 + t;
    int row = f >> 5;
    int c4 = (f & 31) * 4;
    *(float4*)&Al[row][c4] = *(const float4*)(Ab + (cr0 + row) * CC + c4);
  }
  __syncthreads();
  const int tr = t >> 4;
  const int ti8 = (t & 15) * 8;
  float p8[8];
#pragma unroll
  for (int i = 0; i < 8; ++i) p8[i] = 0.f;
  float csum = 0.f;
  const bool do_c0 = ((t & 15) == 0);
  for (int d = 0; d < CC; ++d) {
    float av = Al[tr][d];
    float4 w0 = *(const float4*)&Wv[d][ti8];
    float4 w1 = *(const float4*)&Wv[d][ti8 + 4];
    p8[0] += av * w0.x; p8[1] += av * w0.y; p8[2] += av * w0.z; p8[3] += av * w0.w;
    p8[4] += av * w1.x; p8[5] += av * w1.y; p8[6] += av * w1.z; p8[7] += av * w1.w;
    if (do_c0) csum += av * vb[d];
  }
  float* Pb = P + (size_t)b * CC * CC + (size_t)(cr0 + tr) * CC;
#pragma unroll
  for (int i = 0; i < 8; ++i) Pb[ti8 + i] = p8[i];
  if (do_c0) c0v[b * CC + cr0 + tr] = csum;
}

// ---------------------------------------------------------------------------
// K3: out[im] = x[im] + P[im&7] * x[im] + c0[im&7].  grid (32 chunks, 16 im).
// ---------------------------------------------------------------------------
__global__ __launch_bounds__(256) void k3_out(const float* __restrict__ x,
    const float* __restrict__ P, const float* __restrict__ c0v,
    float* __restrict__ out) {
  const int im = blockIdx.y;
  const int pb = im & 7;
  const int n0 = blockIdx.x * 512;
  const float* X = x + (size_t)im * NFULL;
  float* O = out + (size_t)im * NFULL;
  __shared__ float PT[128][132];   // PT[d][c]
  __shared__ float Xl[128][68];    // [d][n-tile]
  __shared__ float c0l[128];
  const int t = threadIdx.x;
  const float* Pb = P + (size_t)pb * CC * CC;
#pragma unroll
  for (int p = 0; p < 16; ++p) {
    int f = p * 256 + t;
    int row = f >> 5;            // c
    int c4 = (f & 31) * 4;       // d
    float4 v = *(const float4*)(Pb + row * CC + c4);
    PT[c4 + 0][row] = v.x; PT[c4 + 1][row] = v.y;
    PT[c4 + 2][row] = v.z; PT[c4 + 3][row] = v.w;
  }
  if (t < 128) c0l[t] = c0v[pb * CC + t];
  const int tc8 = (t >> 4) * 8;
  const int tn4 = (t & 15) * 4;
  for (int sub = 0; sub < 8; ++sub) {
    const int ns = n0 + sub * 64;
    __syncthreads();
#pragma unroll
    for (int p = 0; p < 8; ++p) {
      int f = p * 256 + t;
      int row = f >> 4;
      int nc = (f & 15) * 4;
      *(float4*)&Xl[row][nc] = *(const float4*)(X + (size_t)row * NSP + ns + nc);
    }
    __syncthreads();
    float acc[8][4];
#pragma unroll
    for (int i = 0; i < 8; ++i)
#pragma unroll
      for (int q = 0; q < 4; ++q) acc[i][q] = 0.f;
#pragma unroll 2
    for (int d = 0; d < CC; ++d) {
      float4 xv = *(const float4*)&Xl[d][tn4];
      float4 p0 = *(const float4*)&PT[d][tc8];
      float4 p1 = *(const float4*)&PT[d][tc8 + 4];
      acc[0][0] += p0.x * xv.x; acc[0][1] += p0.x * xv.y; acc[0][2] += p0.x * xv.z; acc[0][3] += p0.x * xv.w;
      acc[1][0] += p0.y * xv.x; acc[1][1] += p0.y * xv.y; acc[1][2] += p0.y * xv.z; acc[1][3] += p0.y * xv.w;
      acc[2][0] += p0.z * xv.x; acc[2][1] += p0.z * xv.y; acc[2][2] += p0.z * xv.z; acc[2][3] += p0.z * xv.w;
      acc[3][0] += p0.w * xv.x; acc[3][1] += p0.w * xv.y; acc[3][2] += p0.w * xv.z; acc[3][3] += p0.w * xv.w;
      acc[4][0] += p1.x * xv.x; acc[4][1] += p1.x * xv.y; acc[4][2] += p1.x * xv.z; acc[4][3] += p1.x * xv.w;
      acc[5][0] += p1.y * xv.x; acc[5][1] += p1.y * xv.y; acc[5][2] += p1.y * xv.z; acc[5][3] += p1.y * xv.w;
      acc[6][0] += p1.z * xv.x; acc[6][1] += p1.z * xv.y; acc[6][2] += p1.z * xv.z; acc[6][3] += p1.z * xv.w;
      acc[7][0] += p1.w * xv.x; acc[7][1] += p1.w * xv.y; acc[7][2] += p1.w * xv.z; acc[7][3] += p1.w * xv.w;
    }
#pragma unroll
    for (int ccx = 0; ccx < 8; ++ccx) {
      int c = tc8 + ccx;
      float4 xo = *(const float4*)(X + (size_t)c * NSP + ns + tn4);
      float cc0 = c0l[c];
      float4 r;
      r.x = acc[ccx][0] + xo.x + cc0;
      r.y = acc[ccx][1] + xo.y + cc0;
      r.z = acc[ccx][2] + xo.z + cc0;
      r.w = acc[ccx][3] + xo.w + cc0;
      *(float4*)(O + (size_t)c * NSP + ns + tn4) = r;
    }
  }
}

// ---------------------------------------------------------------------------
extern "C" void kernel_launch(void* const* d_in, const int* in_sizes, int n_in,
                              void* d_out, int out_size, void* d_ws, size_t ws_size,
                              hipStream_t stream) {
  (void)in_sizes; (void)n_in; (void)out_size; (void)ws_size;
  const float* x  = (const float*)d_in[0];
  const float* qw = (const float*)d_in[1];
  const float* qb = (const float*)d_in[2];
  const float* kw = (const float*)d_in[3];
  const float* kb = (const float*)d_in[4];
  const float* vw = (const float*)d_in[5];
  const float* vb = (const float*)d_in[6];
  float* out = (float*)d_out;
  float* ws = (float*)d_ws;
  // ws layout (floats): needs ~3.16 MB total
  float* M   = ws;             // 8*128*128
  float* rs  = M + 131072;     // 8*128
  float* rt  = rs + 1024;      // 8*128
  float* T1  = rt + 1024;      // 8*128*128
  float* T2  = T1 + 131072;
  float* AST = T2 + 131072;
  float* ATS = AST + 131072;
  float* ATT = ATS + 131072;
  float* Pm  = ATT + 131072;
  float* usv = Pm + 131072;    // 8*128
  float* utv = usv + 1024;
  float* c0v = utv + 1024;

  hipMemsetAsync(M, 0, (131072 + 2048) * sizeof(float), stream);  // M, rs, rt
  k1_gram<<<dim3(64, 8), 256, 0, stream>>>(x, M, rs, rt);
  k2a<<<dim3(8, 8), 256, 0, stream>>>(M, qw, rs, rt, T1, T2, usv, utv);
  k2b<<<dim3(8, 8, 2), 256, 0, stream>>>(T1, T2, kw, qb, kb, usv, utv, rs, rt, AST, ATS);
  k2c<<<dim3(8, 8), 256, 0, stream>>>(AST, ATS, ATT);
  k2d<<<dim3(8, 8), 256, 0, stream>>>(ATT, vw, vb, Pm, c0v);
  k3_out<<<dim3(32, 16), 256, 0, stream>>>(x, Pm, c0v, out);
}

// Round 2
// 289.869 us; speedup vs baseline: 1.8742x; 1.8742x over previous
//
#include <hip/hip_runtime.h>

#define CC 128
#define NSP 16384              // 128*128 spatial
#define NFULL (CC * NSP)

typedef float f32x4 __attribute__((ext_vector_type(4)));
typedef short s16x8 __attribute__((ext_vector_type(8)));
typedef unsigned int u32x4 __attribute__((ext_vector_type(4)));

// fp32[8] -> bf16 hi frag + bf16 lo frag (truncation split: hi=trunc bf16,
// lo=bf16(x - hi); skipped lo*lo term is ~2^-16 relative -> negligible here)
__device__ __forceinline__ void cvt8(const float* v, s16x8& hi, s16x8& lo) {
  unsigned ph[4], pl[4];
#pragma unroll
  for (int k = 0; k < 4; ++k) {
    unsigned u0 = __float_as_uint(v[2 * k]);
    unsigned u1 = __float_as_uint(v[2 * k + 1]);
    ph[k] = (u1 & 0xFFFF0000u) | (u0 >> 16);
    float h0 = __uint_as_float(u0 & 0xFFFF0000u);
    float h1 = __uint_as_float(u1 & 0xFFFF0000u);
    unsigned l0 = __float_as_uint(v[2 * k] - h0);
    unsigned l1 = __float_as_uint(v[2 * k + 1] - h1);
    pl[k] = (l1 & 0xFFFF0000u) | (l0 >> 16);
  }
  u32x4 H = {ph[0], ph[1], ph[2], ph[3]};
  u32x4 L = {pl[0], pl[1], pl[2], pl[3]};
  hi = __builtin_bit_cast(s16x8, H);
  lo = __builtin_bit_cast(s16x8, L);
}

// ---------------------------------------------------------------------------
// K1 (MFMA): per batch b, chunk c: Mdst = partial Xt*Xs^T over n-chunk.
// Block = 4 waves (2x2), each wave computes 64x64 via 4x4 tiles of 16x16x32
// bf16 MFMA with hi/lo split. Fragments loaded DIRECTLY from global (n is
// contiguous = fragment k-dim). Row sums rt/rs accumulated on the side.
// mode 0: write partials to Mdst[(chunk*8+b)*16384 + ...]; mode 1: atomicAdd
// into Mdst[b*16384 + ...].
// ---------------------------------------------------------------------------
__global__ __launch_bounds__(256, 2) void k1_mfma(const float* __restrict__ x,
    float* __restrict__ Mdst, float* __restrict__ rs, float* __restrict__ rt,
    int nsteps, int mode) {
  const int b = blockIdx.y;
  const int chunk = blockIdx.x;
  const int n0 = chunk * (nsteps * 32);
  const int t = threadIdx.x;
  const int w = t >> 6, l = t & 63;
  const int wr = w >> 1, wc = w & 1;
  const int lr = l & 15;
  const int lk = (l >> 4) << 3;          // 0,8,16,24
  const float* Xs = x + (size_t)b * NFULL;
  const float* Xt = x + (size_t)(b + 8) * NFULL;
  const float* Ab = Xt + (size_t)(wr * 64 + lr) * NSP + n0 + lk;
  const float* Bb = Xs + (size_t)(wc * 64 + lr) * NSP + n0 + lk;

  f32x4 acc[4][4];
#pragma unroll
  for (int a = 0; a < 4; ++a)
#pragma unroll
    for (int bb = 0; bb < 4; ++bb) acc[a][bb] = (f32x4){0.f, 0.f, 0.f, 0.f};
  float rtp[4] = {0.f, 0.f, 0.f, 0.f};
  float rsp[4] = {0.f, 0.f, 0.f, 0.f};

  for (int s = 0; s < nsteps; ++s) {
    const float* ap = Ab + s * 32;
    const float* bp = Bb + s * 32;
    s16x8 ahi[4], alo[4], bhi[4], blo[4];
    {
      float ar[4][8];
#pragma unroll
      for (int a = 0; a < 4; ++a) {
        *(f32x4*)&ar[a][0] = *(const f32x4*)(ap + (size_t)a * 16 * NSP);
        *(f32x4*)&ar[a][4] = *(const f32x4*)(ap + (size_t)a * 16 * NSP + 4);
      }
      if (wc == 0) {
#pragma unroll
        for (int a = 0; a < 4; ++a) {
          float s0 = (ar[a][0] + ar[a][1]) + (ar[a][2] + ar[a][3]);
          float s1 = (ar[a][4] + ar[a][5]) + (ar[a][6] + ar[a][7]);
          rtp[a] += s0 + s1;
        }
      }
#pragma unroll
      for (int a = 0; a < 4; ++a) cvt8(ar[a], ahi[a], alo[a]);
    }
    {
      float br[4][8];
#pragma unroll
      for (int bb = 0; bb < 4; ++bb) {
        *(f32x4*)&br[bb][0] = *(const f32x4*)(bp + (size_t)bb * 16 * NSP);
        *(f32x4*)&br[bb][4] = *(const f32x4*)(bp + (size_t)bb * 16 * NSP + 4);
      }
      if (wr == 0) {
#pragma unroll
        for (int bb = 0; bb < 4; ++bb) {
          float s0 = (br[bb][0] + br[bb][1]) + (br[bb][2] + br[bb][3]);
          float s1 = (br[bb][4] + br[bb][5]) + (br[bb][6] + br[bb][7]);
          rsp[bb] += s0 + s1;
        }
      }
#pragma unroll
      for (int bb = 0; bb < 4; ++bb) cvt8(br[bb], bhi[bb], blo[bb]);
    }
#pragma unroll
    for (int a = 0; a < 4; ++a)
#pragma unroll
      for (int bb = 0; bb < 4; ++bb) {
        acc[a][bb] = __builtin_amdgcn_mfma_f32_16x16x32_bf16(ahi[a], bhi[bb], acc[a][bb], 0, 0, 0);
        acc[a][bb] = __builtin_amdgcn_mfma_f32_16x16x32_bf16(ahi[a], blo[bb], acc[a][bb], 0, 0, 0);
        acc[a][bb] = __builtin_amdgcn_mfma_f32_16x16x32_bf16(alo[a], bhi[bb], acc[a][bb], 0, 0, 0);
      }
  }

  // row-sum reduction across the 4 k-groups (lanes l, l^16, l^32, l^48)
  if (wc == 0) {
#pragma unroll
    for (int a = 0; a < 4; ++a) {
      float v = rtp[a];
      v += __shfl_xor(v, 16);
      v += __shfl_xor(v, 32);
      if (l < 16) atomicAdd(&rt[b * CC + wr * 64 + a * 16 + l], v);
    }
  }
  if (wr == 0) {
#pragma unroll
    for (int bb = 0; bb < 4; ++bb) {
      float v = rsp[bb];
      v += __shfl_xor(v, 16);
      v += __shfl_xor(v, 32);
      if (l < 16) atomicAdd(&rs[b * CC + wc * 64 + bb * 16 + l], v);
    }
  }

  const int rquad = (l >> 4) << 2;       // D row base within tile
  if (mode == 0) {
    float* Mp = Mdst + ((size_t)chunk * 8 + b) * (CC * CC);
#pragma unroll
    for (int a = 0; a < 4; ++a)
#pragma unroll
      for (int bb = 0; bb < 4; ++bb)
#pragma unroll
        for (int r = 0; r < 4; ++r) {
          int i = wr * 64 + a * 16 + rquad + r;
          int j = wc * 64 + bb * 16 + lr;
          Mp[i * CC + j] = acc[a][bb][r];
        }
  } else {
    float* Mp = Mdst + (size_t)b * (CC * CC);
#pragma unroll
    for (int a = 0; a < 4; ++a)
#pragma unroll
      for (int bb = 0; bb < 4; ++bb)
#pragma unroll
        for (int r = 0; r < 4; ++r) {
          int i = wr * 64 + a * 16 + rquad + r;
          int j = wc * 64 + bb * 16 + lr;
          atomicAdd(&Mp[i * CC + j], acc[a][bb][r]);
        }
  }
}

// Sum partials: M[b][e] = sum_c Mpart[(c*8+b)*16384 + e]
__global__ __launch_bounds__(256) void k1_reduce(const float* __restrict__ Mpart,
    float* __restrict__ M, int NB) {
  const int idx = blockIdx.x * 256 + threadIdx.x;   // < 131072
  const int b = idx >> 14, e = idx & 16383;
  float s = 0.f;
  for (int c = 0; c < NB; ++c) s += Mpart[((size_t)c * 8 + b) * (CC * CC) + e];
  M[idx] = s;
}

// ---------------------------------------------------------------------------
// K2a: T1 = Wq*M, T2 = Wq*M^T, us = Wq*rs, ut = Wq*rt.  grid (8 rowgrp, 8 b).
// ---------------------------------------------------------------------------
__global__ __launch_bounds__(256) void k2a(const float* __restrict__ M,
    const float* __restrict__ qw, const float* __restrict__ rs,
    const float* __restrict__ rt, float* __restrict__ T1, float* __restrict__ T2,
    float* __restrict__ us, float* __restrict__ ut) {
  const int b = blockIdx.y;
  const int c0 = blockIdx.x * 16;
  __shared__ float Ml[128][129];
  __shared__ float Wq[16][128];
  const int t = threadIdx.x;
  const float* Mb = M + (size_t)b * CC * CC;
#pragma unroll
  for (int p = 0; p < 16; ++p) {
    int f = p * 256 + t;
    int row = f >> 5;
    int c4 = (f & 31) * 4;
    float4 v = *(const float4*)(Mb + row * CC + c4);
    Ml[row][c4 + 0] = v.x; Ml[row][c4 + 1] = v.y;
    Ml[row][c4 + 2] = v.z; Ml[row][c4 + 3] = v.w;
  }
#pragma unroll
  for (int p = 0; p < 2; ++p) {
    int f = p * 256 + t;
    int row = f >> 5;
    int c4 = (f & 31) * 4;
    *(float4*)&Wq[row][c4] = *(const float4*)(qw + (c0 + row) * CC + c4);
  }
  __syncthreads();
  if (t < 32) {                       // u vectors (bias fix-up terms)
    int c = t & 15;
    const float* r = (t < 16) ? rs : rt;
    float s = 0.f;
    for (int i = 0; i < CC; ++i) s += Wq[c][i] * r[b * CC + i];
    if (t < 16) us[b * CC + c0 + c] = s;
    else        ut[b * CC + c0 + c] = s;
  }
  const int tr = t >> 4;
  const int tj8 = (t & 15) * 8;
  float a1[8], a2[8];
#pragma unroll
  for (int j = 0; j < 8; ++j) { a1[j] = 0.f; a2[j] = 0.f; }
  for (int i = 0; i < CC; ++i) {
    float wq = Wq[tr][i];
#pragma unroll
    for (int j = 0; j < 8; ++j) {
      a1[j] += wq * Ml[i][tj8 + j];        // (Wq M)[c][j]
      a2[j] += wq * Ml[tj8 + j][i];        // (Wq M^T)[c][j]
    }
  }
  float* T1b = T1 + (size_t)b * CC * CC + (size_t)(c0 + tr) * CC;
  float* T2b = T2 + (size_t)b * CC * CC + (size_t)(c0 + tr) * CC;
#pragma unroll
  for (int j = 0; j < 8; ++j) { T1b[tj8 + j] = a1[j]; T2b[tj8 + j] = a2[j]; }
}

// ---------------------------------------------------------------------------
// K2b: G = T*Wk^T + u*bk^T + bq*w^T + N*bq*bk^T, row-softmax -> A.
// ---------------------------------------------------------------------------
__global__ __launch_bounds__(256) void k2b(const float* __restrict__ T1,
    const float* __restrict__ T2, const float* __restrict__ kw,
    const float* __restrict__ qb, const float* __restrict__ kb,
    const float* __restrict__ us, const float* __restrict__ ut,
    const float* __restrict__ rs, const float* __restrict__ rt,
    float* __restrict__ Ast, float* __restrict__ Ats) {
  const int b = blockIdx.y;
  const int c0 = blockIdx.x * 16;
  const int which = blockIdx.z;
  __shared__ float Wk[128][129];
  __shared__ float Tl[16][128];
  __shared__ float wv[128];
  __shared__ float uv[16];
  const int t = threadIdx.x;
  const float* Tm = which ? (T2 + (size_t)b * CC * CC) : (T1 + (size_t)b * CC * CC);
#pragma unroll
  for (int p = 0; p < 16; ++p) {
    int f = p * 256 + t;
    int row = f >> 5;
    int c4 = (f & 31) * 4;
    float4 v = *(const float4*)(kw + row * CC + c4);
    Wk[row][c4 + 0] = v.x; Wk[row][c4 + 1] = v.y;
    Wk[row][c4 + 2] = v.z; Wk[row][c4 + 3] = v.w;
  }
#pragma unroll
  for (int p = 0; p < 2; ++p) {
    int f = p * 256 + t;
    int row = f >> 5;
    int c4 = (f & 31) * 4;
    *(float4*)&Tl[row][c4] = *(const float4*)(Tm + (c0 + row) * CC + c4);
  }
  if (t < 16) uv[t] = (which ? us : ut)[b * CC + c0 + t];
  __syncthreads();
  if (t < 128) {
    const float* r = (which ? rt : rs) + b * CC;
    float s = 0.f;
    for (int j = 0; j < CC; ++j) s += Wk[t][j] * r[j];
    wv[t] = s;
  }
  __syncthreads();
  const int tr = t >> 4;
  const int td8 = (t & 15) * 8;
  const int c = c0 + tr;
  const float bqc = qb[c];
  float g[8];
#pragma unroll
  for (int dd = 0; dd < 8; ++dd) {
    int d = td8 + dd;
    g[dd] = uv[tr] * kb[d] + bqc * wv[d] + 16384.f * bqc * kb[d];
  }
  for (int j = 0; j < CC; ++j) {
    float tv = Tl[tr][j];
#pragma unroll
    for (int dd = 0; dd < 8; ++dd) g[dd] += tv * Wk[td8 + dd][j];
  }
  float m = g[0];
#pragma unroll
  for (int dd = 1; dd < 8; ++dd) m = fmaxf(m, g[dd]);
#pragma unroll
  for (int off = 1; off < 16; off <<= 1) m = fmaxf(m, __shfl_xor(m, off));
  float s = 0.f;
#pragma unroll
  for (int dd = 0; dd < 8; ++dd) { g[dd] = expf(g[dd] - m); s += g[dd]; }
#pragma unroll
  for (int off = 1; off < 16; off <<= 1) s += __shfl_xor(s, off);
  const float inv = 1.f / s;
  float* A = (which ? Ats : Ast) + (size_t)b * CC * CC + (size_t)c * CC;
#pragma unroll
  for (int dd = 0; dd < 8; ++dd) A[td8 + dd] = g[dd] * inv;
}

// ---------------------------------------------------------------------------
// K2c: L = Ast * Ats^T, row-softmax -> Att.  grid (8 rowgrp, 8 b).
// ---------------------------------------------------------------------------
__global__ __launch_bounds__(256) void k2c(const float* __restrict__ Ast,
    const float* __restrict__ Ats, float* __restrict__ Att) {
  const int b = blockIdx.y;
  const int c0 = blockIdx.x * 16;
  __shared__ float Bl[128][129];
  __shared__ float Tl[16][128];
  const int t = threadIdx.x;
  const float* Bb = Ats + (size_t)b * CC * CC;
  const float* Tb = Ast + (size_t)b * CC * CC;
#pragma unroll
  for (int p = 0; p < 16; ++p) {
    int f = p * 256 + t;
    int row = f >> 5;
    int c4 = (f & 31) * 4;
    float4 v = *(const float4*)(Bb + row * CC + c4);
    Bl[row][c4 + 0] = v.x; Bl[row][c4 + 1] = v.y;
    Bl[row][c4 + 2] = v.z; Bl[row][c4 + 3] = v.w;
  }
#pragma unroll
  for (int p = 0; p < 2; ++p) {
    int f = p * 256 + t;
    int row = f >> 5;
    int c4 = (f & 31) * 4;
    *(float4*)&Tl[row][c4] = *(const float4*)(Tb + (c0 + row) * CC + c4);
  }
  __syncthreads();
  const int tr = t >> 4;
  const int td8 = (t & 15) * 8;
  float g[8];
#pragma unroll
  for (int dd = 0; dd < 8; ++dd) g[dd] = 0.f;
  for (int e = 0; e < CC; ++e) {
    float tv = Tl[tr][e];
#pragma unroll
    for (int dd = 0; dd < 8; ++dd) g[dd] += tv * Bl[td8 + dd][e];
  }
  float m = g[0];
#pragma unroll
  for (int dd = 1; dd < 8; ++dd) m = fmaxf(m, g[dd]);
#pragma unroll
  for (int off = 1; off < 16; off <<= 1) m = fmaxf(m, __shfl_xor(m, off));
  float s = 0.f;
#pragma unroll
  for (int dd = 0; dd < 8; ++dd) { g[dd] = expf(g[dd] - m); s += g[dd]; }
#pragma unroll
  for (int off = 1; off < 16; off <<= 1) s += __shfl_xor(s, off);
  const float inv = 1.f / s;
  float* A = Att + (size_t)b * CC * CC + (size_t)(c0 + tr) * CC;
#pragma unroll
  for (int dd = 0; dd < 8; ++dd) A[td8 + dd] = g[dd] * inv;
}

// ---------------------------------------------------------------------------
// K2d: P = Att*Wv, c0 = Att*bv.  grid (8 rowgrp, 8 b).
// ---------------------------------------------------------------------------
__global__ __launch_bounds__(256) void k2d(const float* __restrict__ Att,
    const float* __restrict__ vw, const float* __restrict__ vb,
    float* __restrict__ P, float* __restrict__ c0v) {
  const int b = blockIdx.y;
  const int cr0 = blockIdx.x * 16;
  __shared__ float Wv[128][132];
  __shared__ float Al[16][128];
  const int t = threadIdx.x;
  const float* Ab = Att + (size_t)b * CC * CC;
#pragma unroll
  for (int p = 0; p < 16; ++p) {
    int f = p * 256 + t;
    int row = f >> 5;
    int c4 = (f & 31) * 4;
    *(float4*)&Wv[row][c4] = *(const float4*)(vw + row * CC + c4);
  }
#pragma unroll
  for (int p = 0; p < 2; ++p) {
    int f = p * 256 + t;
    int row = f >> 5;
    int c4 = (f & 31) * 4;
    *(float4*)&Al[row][c4] = *(const float4*)(Ab + (cr0 + row) * CC + c4);
  }
  __syncthreads();
  const int tr = t >> 4;
  const int ti8 = (t & 15) * 8;
  float p8[8];
#pragma unroll
  for (int i = 0; i < 8; ++i) p8[i] = 0.f;
  float csum = 0.f;
  const bool do_c0 = ((t & 15) == 0);
  for (int d = 0; d < CC; ++d) {
    float av = Al[tr][d];
    float4 w0 = *(const float4*)&Wv[d][ti8];
    float4 w1 = *(const float4*)&Wv[d][ti8 + 4];
    p8[0] += av * w0.x; p8[1] += av * w0.y; p8[2] += av * w0.z; p8[3] += av * w0.w;
    p8[4] += av * w1.x; p8[5] += av * w1.y; p8[6] += av * w1.z; p8[7] += av * w1.w;
    if (do_c0) csum += av * vb[d];
  }
  float* Pb = P + (size_t)b * CC * CC + (size_t)(cr0 + tr) * CC;
#pragma unroll
  for (int i = 0; i < 8; ++i) Pb[ti8 + i] = p8[i];
  if (do_c0) c0v[b * CC + cr0 + tr] = csum;
}

// ---------------------------------------------------------------------------
// K3: out[im] = x[im] + P[im&7]*x[im] + c0[im&7]. No X staging: 4 waves of a
// block read the same 256B X segments (L1 broadcast). PT only in LDS (68KB)
// -> 2 blocks/CU. grid (32 n-chunks of 512, 16 im).
// ---------------------------------------------------------------------------
__global__ __launch_bounds__(256, 2) void k3_out(const float* __restrict__ x,
    const float* __restrict__ P, const float* __restrict__ c0v,
    float* __restrict__ out) {
  const int im = blockIdx.y;
  const int pb = im & 7;
  const int nb0 = blockIdx.x * 512;
  const float* X = x + (size_t)im * NFULL;
  float* O = out + (size_t)im * NFULL;
  __shared__ float PT[128][132];   // PT[d][c]
  __shared__ float c0l[128];
  const int t = threadIdx.x;
  const float* Pb = P + (size_t)pb * CC * CC;
#pragma unroll
  for (int p = 0; p < 16; ++p) {
    int f = p * 256 + t;
    int row = f >> 5;            // c
    int c4 = (f & 31) * 4;       // d
    float4 v = *(const float4*)(Pb + row * CC + c4);
    PT[c4 + 0][row] = v.x; PT[c4 + 1][row] = v.y;
    PT[c4 + 2][row] = v.z; PT[c4 + 3][row] = v.w;
  }
  if (t < 128) c0l[t] = c0v[pb * CC + t];
  __syncthreads();
  const int tc8 = (t >> 4) * 8;
  const int tn4 = (t & 15) * 4;
  for (int tile = 0; tile < 8; ++tile) {
    const int ns = nb0 + tile * 64;
    const float* Xc = X + ns + tn4;
    float acc[8][4];
#pragma unroll
    for (int i = 0; i < 8; ++i)
#pragma unroll
      for (int q = 0; q < 4; ++q) acc[i][q] = 0.f;
#pragma unroll 4
    for (int d = 0; d < 128; ++d) {
      f32x4 xv = *(const f32x4*)(Xc + (size_t)d * NSP);
      f32x4 p0 = *(const f32x4*)&PT[d][tc8];
      f32x4 p1 = *(const f32x4*)&PT[d][tc8 + 4];
      acc[0][0] += p0[0] * xv[0]; acc[0][1] += p0[0] * xv[1]; acc[0][2] += p0[0] * xv[2]; acc[0][3] += p0[0] * xv[3];
      acc[1][0] += p0[1] * xv[0]; acc[1][1] += p0[1] * xv[1]; acc[1][2] += p0[1] * xv[2]; acc[1][3] += p0[1] * xv[3];
      acc[2][0] += p0[2] * xv[0]; acc[2][1] += p0[2] * xv[1]; acc[2][2] += p0[2] * xv[2]; acc[2][3] += p0[2] * xv[3];
      acc[3][0] += p0[3] * xv[0]; acc[3][1] += p0[3] * xv[1]; acc[3][2] += p0[3] * xv[2]; acc[3][3] += p0[3] * xv[3];
      acc[4][0] += p1[0] * xv[0]; acc[4][1] += p1[0] * xv[1]; acc[4][2] += p1[0] * xv[2]; acc[4][3] += p1[0] * xv[3];
      acc[5][0] += p1[1] * xv[0]; acc[5][1] += p1[1] * xv[1]; acc[5][2] += p1[1] * xv[2]; acc[5][3] += p1[1] * xv[3];
      acc[6][0] += p1[2] * xv[0]; acc[6][1] += p1[2] * xv[1]; acc[6][2] += p1[2] * xv[2]; acc[6][3] += p1[2] * xv[3];
      acc[7][0] += p1[3] * xv[0]; acc[7][1] += p1[3] * xv[1]; acc[7][2] += p1[3] * xv[2]; acc[7][3] += p1[3] * xv[3];
    }
#pragma unroll
    for (int i = 0; i < 8; ++i) {
      const int c = tc8 + i;
      f32x4 xo = *(const f32x4*)(X + (size_t)c * NSP + ns + tn4);
      const float cc0 = c0l[c];
      f32x4 r;
      r[0] = acc[i][0] + xo[0] + cc0;
      r[1] = acc[i][1] + xo[1] + cc0;
      r[2] = acc[i][2] + xo[2] + cc0;
      r[3] = acc[i][3] + xo[3] + cc0;
      *(f32x4*)(O + (size_t)c * NSP + ns + tn4) = r;
    }
  }
}

// ---------------------------------------------------------------------------
extern "C" void kernel_launch(void* const* d_in, const int* in_sizes, int n_in,
                              void* d_out, int out_size, void* d_ws, size_t ws_size,
                              hipStream_t stream) {
  (void)in_sizes; (void)n_in; (void)out_size;
  const float* x  = (const float*)d_in[0];
  const float* qw = (const float*)d_in[1];
  const float* qb = (const float*)d_in[2];
  const float* kw = (const float*)d_in[3];
  const float* kb = (const float*)d_in[4];
  const float* vw = (const float*)d_in[5];
  const float* vb = (const float*)d_in[6];
  float* out = (float*)d_out;
  float* ws = (float*)d_ws;
  float* M   = ws;             // 8*128*128
  float* rs  = M + 131072;     // 8*128
  float* rt  = rs + 1024;
  float* T1  = rt + 1024;
  float* T2  = T1 + 131072;
  float* AST = T2 + 131072;
  float* ATS = AST + 131072;
  float* ATT = ATS + 131072;
  float* Pm  = ATT + 131072;
  float* usv = Pm + 131072;
  float* utv = usv + 1024;
  float* c0v = utv + 1024;
  float* Mpart = c0v + 1024;
  const size_t base_floats = (size_t)(Mpart - ws);

  int NB, mode;
  if (ws_size >= (base_floats + (size_t)64 * 131072) * 4) { NB = 64; mode = 0; }
  else if (ws_size >= (base_floats + (size_t)32 * 131072) * 4) { NB = 32; mode = 0; }
  else { NB = 32; mode = 1; }
  const int nsteps = (16384 / NB) / 32;

  hipMemsetAsync(M, 0, (131072 + 2048) * sizeof(float), stream);  // M, rs, rt
  k1_mfma<<<dim3(NB, 8), 256, 0, stream>>>(x, mode ? M : Mpart, rs, rt, nsteps, mode);
  if (mode == 0) k1_reduce<<<512, 256, 0, stream>>>(Mpart, M, NB);
  k2a<<<dim3(8, 8), 256, 0, stream>>>(M, qw, rs, rt, T1, T2, usv, utv);
  k2b<<<dim3(8, 8, 2), 256, 0, stream>>>(T1, T2, kw, qb, kb, usv, utv, rs, rt, AST, ATS);
  k2c<<<dim3(8, 8), 256, 0, stream>>>(AST, ATS, ATT);
  k2d<<<dim3(8, 8), 256, 0, stream>>>(ATT, vw, vb, Pm, c0v);
  k3_out<<<dim3(32, 16), 256, 0, stream>>>(x, Pm, c0v, out);
}

// Round 3
// 207.127 us; speedup vs baseline: 2.6229x; 1.3995x over previous
//
#include <hip/hip_runtime.h>

#define CC 128
#define NSP 16384              // 128*128 spatial
#define NFULL (CC * NSP)

typedef float f32x4 __attribute__((ext_vector_type(4)));
typedef short s16x8 __attribute__((ext_vector_type(8)));
typedef unsigned int u32x4 __attribute__((ext_vector_type(4)));

__device__ __forceinline__ unsigned bf16rne(float f) {
  unsigned u = __float_as_uint(f);
  return ((u + 0x7FFFu + ((u >> 16) & 1u)) >> 16) & 0xFFFFu;
}

// fp32[8] -> bf16 hi frag + bf16 lo frag (for K1 hi/lo split)
__device__ __forceinline__ void cvt8(const float* v, s16x8& hi, s16x8& lo) {
  unsigned ph[4], pl[4];
#pragma unroll
  for (int k = 0; k < 4; ++k) {
    unsigned u0 = __float_as_uint(v[2 * k]);
    unsigned u1 = __float_as_uint(v[2 * k + 1]);
    ph[k] = (u1 & 0xFFFF0000u) | (u0 >> 16);
    float h0 = __uint_as_float(u0 & 0xFFFF0000u);
    float h1 = __uint_as_float(u1 & 0xFFFF0000u);
    unsigned l0 = __float_as_uint(v[2 * k] - h0);
    unsigned l1 = __float_as_uint(v[2 * k + 1] - h1);
    pl[k] = (l1 & 0xFFFF0000u) | (l0 >> 16);
  }
  u32x4 H = {ph[0], ph[1], ph[2], ph[3]};
  u32x4 L = {pl[0], pl[1], pl[2], pl[3]};
  hi = __builtin_bit_cast(s16x8, H);
  lo = __builtin_bit_cast(s16x8, L);
}

// ---------------------------------------------------------------------------
// K1 (MFMA): per batch b, chunk: partial Xt*Xs^T over n-chunk (hi/lo split).
// ---------------------------------------------------------------------------
__global__ __launch_bounds__(256, 2) void k1_mfma(const float* __restrict__ x,
    float* __restrict__ Mdst, float* __restrict__ rs, float* __restrict__ rt,
    int nsteps, int mode) {
  const int b = blockIdx.y;
  const int chunk = blockIdx.x;
  const int n0 = chunk * (nsteps * 32);
  const int t = threadIdx.x;
  const int w = t >> 6, l = t & 63;
  const int wr = w >> 1, wc = w & 1;
  const int lr = l & 15;
  const int lk = (l >> 4) << 3;
  const float* Xs = x + (size_t)b * NFULL;
  const float* Xt = x + (size_t)(b + 8) * NFULL;
  const float* Ab = Xt + (size_t)(wr * 64 + lr) * NSP + n0 + lk;
  const float* Bb = Xs + (size_t)(wc * 64 + lr) * NSP + n0 + lk;

  f32x4 acc[4][4];
#pragma unroll
  for (int a = 0; a < 4; ++a)
#pragma unroll
    for (int bb = 0; bb < 4; ++bb) acc[a][bb] = (f32x4){0.f, 0.f, 0.f, 0.f};
  float rtp[4] = {0.f, 0.f, 0.f, 0.f};
  float rsp[4] = {0.f, 0.f, 0.f, 0.f};

  for (int s = 0; s < nsteps; ++s) {
    const float* ap = Ab + s * 32;
    const float* bp = Bb + s * 32;
    s16x8 ahi[4], alo[4], bhi[4], blo[4];
    {
      float ar[4][8];
#pragma unroll
      for (int a = 0; a < 4; ++a) {
        *(f32x4*)&ar[a][0] = *(const f32x4*)(ap + (size_t)a * 16 * NSP);
        *(f32x4*)&ar[a][4] = *(const f32x4*)(ap + (size_t)a * 16 * NSP + 4);
      }
      if (wc == 0) {
#pragma unroll
        for (int a = 0; a < 4; ++a) {
          float s0 = (ar[a][0] + ar[a][1]) + (ar[a][2] + ar[a][3]);
          float s1 = (ar[a][4] + ar[a][5]) + (ar[a][6] + ar[a][7]);
          rtp[a] += s0 + s1;
        }
      }
#pragma unroll
      for (int a = 0; a < 4; ++a) cvt8(ar[a], ahi[a], alo[a]);
    }
    {
      float br[4][8];
#pragma unroll
      for (int bb = 0; bb < 4; ++bb) {
        *(f32x4*)&br[bb][0] = *(const f32x4*)(bp + (size_t)bb * 16 * NSP);
        *(f32x4*)&br[bb][4] = *(const f32x4*)(bp + (size_t)bb * 16 * NSP + 4);
      }
      if (wr == 0) {
#pragma unroll
        for (int bb = 0; bb < 4; ++bb) {
          float s0 = (br[bb][0] + br[bb][1]) + (br[bb][2] + br[bb][3]);
          float s1 = (br[bb][4] + br[bb][5]) + (br[bb][6] + br[bb][7]);
          rsp[bb] += s0 + s1;
        }
      }
#pragma unroll
      for (int bb = 0; bb < 4; ++bb) cvt8(br[bb], bhi[bb], blo[bb]);
    }
#pragma unroll
    for (int a = 0; a < 4; ++a)
#pragma unroll
      for (int bb = 0; bb < 4; ++bb) {
        acc[a][bb] = __builtin_amdgcn_mfma_f32_16x16x32_bf16(ahi[a], bhi[bb], acc[a][bb], 0, 0, 0);
        acc[a][bb] = __builtin_amdgcn_mfma_f32_16x16x32_bf16(ahi[a], blo[bb], acc[a][bb], 0, 0, 0);
        acc[a][bb] = __builtin_amdgcn_mfma_f32_16x16x32_bf16(alo[a], bhi[bb], acc[a][bb], 0, 0, 0);
      }
  }

  if (wc == 0) {
#pragma unroll
    for (int a = 0; a < 4; ++a) {
      float v = rtp[a];
      v += __shfl_xor(v, 16);
      v += __shfl_xor(v, 32);
      if (l < 16) atomicAdd(&rt[b * CC + wr * 64 + a * 16 + l], v);
    }
  }
  if (wr == 0) {
#pragma unroll
    for (int bb = 0; bb < 4; ++bb) {
      float v = rsp[bb];
      v += __shfl_xor(v, 16);
      v += __shfl_xor(v, 32);
      if (l < 16) atomicAdd(&rs[b * CC + wc * 64 + bb * 16 + l], v);
    }
  }

  const int rquad = (l >> 4) << 2;
  if (mode == 0) {
    float* Mp = Mdst + ((size_t)chunk * 8 + b) * (CC * CC);
#pragma unroll
    for (int a = 0; a < 4; ++a)
#pragma unroll
      for (int bb = 0; bb < 4; ++bb)
#pragma unroll
        for (int r = 0; r < 4; ++r) {
          int i = wr * 64 + a * 16 + rquad + r;
          int j = wc * 64 + bb * 16 + lr;
          Mp[i * CC + j] = acc[a][bb][r];
        }
  } else {
    float* Mp = Mdst + (size_t)b * (CC * CC);
#pragma unroll
    for (int a = 0; a < 4; ++a)
#pragma unroll
      for (int bb = 0; bb < 4; ++bb)
#pragma unroll
        for (int r = 0; r < 4; ++r) {
          int i = wr * 64 + a * 16 + rquad + r;
          int j = wc * 64 + bb * 16 + lr;
          atomicAdd(&Mp[i * CC + j], acc[a][bb][r]);
        }
  }
}

__global__ __launch_bounds__(256) void k1_reduce(const float* __restrict__ Mpart,
    float* __restrict__ M, int NB) {
  const int idx = blockIdx.x * 256 + threadIdx.x;
  const int b = idx >> 14, e = idx & 16383;
  float s = 0.f;
  for (int c = 0; c < NB; ++c) s += Mpart[((size_t)c * 8 + b) * (CC * CC) + e];
  M[idx] = s;
}

// ---------------------------------------------------------------------------
// K2ab fused: T1=Wq*M, T2=Wq*M^T (kept in LDS), us/ut, then G + softmax for
// both 'st' (which=0) and 'ts' (which=1). grid (8 c-groups, 8 b).
// ---------------------------------------------------------------------------
__global__ __launch_bounds__(256) void k2ab(const float* __restrict__ M,
    const float* __restrict__ qw, const float* __restrict__ kw,
    const float* __restrict__ qb, const float* __restrict__ kb,
    const float* __restrict__ rs, const float* __restrict__ rt,
    float* __restrict__ Ast, float* __restrict__ Ats) {
  const int b = blockIdx.y;
  const int c0 = blockIdx.x * 16;
  __shared__ float Big[128][129];      // M, later Wk
  __shared__ float Wq[16][128];
  __shared__ float T12[2][16][128];    // [0]=T1 rows, [1]=T2 rows
  __shared__ float uvv[2][16];         // [0]=ut (st), [1]=us (ts)
  __shared__ float wv2[2][128];        // [0]=Wk*rs (st), [1]=Wk*rt (ts)
  const int t = threadIdx.x;
  const float* Mb = M + (size_t)b * CC * CC;
#pragma unroll
  for (int p = 0; p < 16; ++p) {
    int f = p * 256 + t;
    int row = f >> 5, c4 = (f & 31) * 4;
    float4 v = *(const float4*)(Mb + row * CC + c4);
    Big[row][c4 + 0] = v.x; Big[row][c4 + 1] = v.y;
    Big[row][c4 + 2] = v.z; Big[row][c4 + 3] = v.w;
  }
#pragma unroll
  for (int p = 0; p < 2; ++p) {
    int f = p * 256 + t;
    int row = f >> 5, c4 = (f & 31) * 4;
    *(float4*)&Wq[row][c4] = *(const float4*)(qw + (c0 + row) * CC + c4);
  }
  __syncthreads();
  if (t < 32) {
    int c = t & 15;
    const float* r = (t < 16) ? rs : rt;
    float s = 0.f;
    for (int i = 0; i < CC; ++i) s += Wq[c][i] * r[b * CC + i];
    uvv[(t < 16) ? 1 : 0][c] = s;      // us->[1], ut->[0]
  }
  const int tr = t >> 4;
  const int td8 = (t & 15) * 8;
  {
    float a1[8], a2[8];
#pragma unroll
    for (int j = 0; j < 8; ++j) { a1[j] = 0.f; a2[j] = 0.f; }
    for (int i = 0; i < CC; ++i) {
      float wq = Wq[tr][i];
#pragma unroll
      for (int j = 0; j < 8; ++j) {
        a1[j] += wq * Big[i][td8 + j];
        a2[j] += wq * Big[td8 + j][i];
      }
    }
#pragma unroll
    for (int j = 0; j < 8; ++j) { T12[0][tr][td8 + j] = a1[j]; T12[1][tr][td8 + j] = a2[j]; }
  }
  __syncthreads();
  // overwrite Big with Wk
#pragma unroll
  for (int p = 0; p < 16; ++p) {
    int f = p * 256 + t;
    int row = f >> 5, c4 = (f & 31) * 4;
    float4 v = *(const float4*)(kw + row * CC + c4);
    Big[row][c4 + 0] = v.x; Big[row][c4 + 1] = v.y;
    Big[row][c4 + 2] = v.z; Big[row][c4 + 3] = v.w;
  }
  __syncthreads();
  {
    int d = t & 127;
    int wh = t >> 7;                   // 0: rs, 1: rt
    const float* r = (wh ? rt : rs) + b * CC;
    float s = 0.f;
    for (int j = 0; j < CC; ++j) s += Big[d][j] * r[j];
    wv2[wh][d] = s;
  }
  __syncthreads();
  const int c = c0 + tr;
  const float bqc = qb[c];
#pragma unroll 1
  for (int which = 0; which < 2; ++which) {
    float g[8];
#pragma unroll
    for (int dd = 0; dd < 8; ++dd) {
      int d = td8 + dd;
      g[dd] = uvv[which][tr] * kb[d] + bqc * wv2[which][d] + 16384.f * bqc * kb[d];
    }
    for (int j = 0; j < CC; ++j) {
      float tv = T12[which][tr][j];
#pragma unroll
      for (int dd = 0; dd < 8; ++dd) g[dd] += tv * Big[td8 + dd][j];
    }
    float m = g[0];
#pragma unroll
    for (int dd = 1; dd < 8; ++dd) m = fmaxf(m, g[dd]);
#pragma unroll
    for (int off = 1; off < 16; off <<= 1) m = fmaxf(m, __shfl_xor(m, off));
    float s = 0.f;
#pragma unroll
    for (int dd = 0; dd < 8; ++dd) { g[dd] = expf(g[dd] - m); s += g[dd]; }
#pragma unroll
    for (int off = 1; off < 16; off <<= 1) s += __shfl_xor(s, off);
    const float inv = 1.f / s;
    float* A = (which ? Ats : Ast) + (size_t)b * CC * CC + (size_t)c * CC;
#pragma unroll
    for (int dd = 0; dd < 8; ++dd) A[td8 + dd] = g[dd] * inv;
  }
}

// ---------------------------------------------------------------------------
// K2cd fused: L = Ast*Ats^T, softmax -> Att (LDS), then P = Att*Wv (-> bf16),
// c0 = Att*bv.  grid (8 c-groups, 8 b).
// ---------------------------------------------------------------------------
__global__ __launch_bounds__(256) void k2cd(const float* __restrict__ Ast,
    const float* __restrict__ Ats, const float* __restrict__ vw,
    const float* __restrict__ vb, unsigned short* __restrict__ Pbf,
    float* __restrict__ c0v) {
  const int b = blockIdx.y;
  const int c0 = blockIdx.x * 16;
  __shared__ float Big[128][132];      // Ats, later Wv[d][i]
  __shared__ float Tl[16][128];        // Ast rows
  __shared__ float Al[16][128];        // Att rows
  const int t = threadIdx.x;
  const float* Bb = Ats + (size_t)b * CC * CC;
  const float* Tb = Ast + (size_t)b * CC * CC;
#pragma unroll
  for (int p = 0; p < 16; ++p) {
    int f = p * 256 + t;
    int row = f >> 5, c4 = (f & 31) * 4;
    *(float4*)&Big[row][c4] = *(const float4*)(Bb + row * CC + c4);
  }
#pragma unroll
  for (int p = 0; p < 2; ++p) {
    int f = p * 256 + t;
    int row = f >> 5, c4 = (f & 31) * 4;
    *(float4*)&Tl[row][c4] = *(const float4*)(Tb + (c0 + row) * CC + c4);
  }
  __syncthreads();
  const int tr = t >> 4;
  const int td8 = (t & 15) * 8;
  {
    float g[8];
#pragma unroll
    for (int dd = 0; dd < 8; ++dd) g[dd] = 0.f;
    for (int e = 0; e < CC; ++e) {
      float tv = Tl[tr][e];
#pragma unroll
      for (int dd = 0; dd < 8; ++dd) g[dd] += tv * Big[td8 + dd][e];
    }
    float m = g[0];
#pragma unroll
    for (int dd = 1; dd < 8; ++dd) m = fmaxf(m, g[dd]);
#pragma unroll
    for (int off = 1; off < 16; off <<= 1) m = fmaxf(m, __shfl_xor(m, off));
    float s = 0.f;
#pragma unroll
    for (int dd = 0; dd < 8; ++dd) { g[dd] = expf(g[dd] - m); s += g[dd]; }
#pragma unroll
    for (int off = 1; off < 16; off <<= 1) s += __shfl_xor(s, off);
    const float inv = 1.f / s;
#pragma unroll
    for (int dd = 0; dd < 8; ++dd) Al[tr][td8 + dd] = g[dd] * inv;
  }
  __syncthreads();
  // overwrite Big with Wv[d][i]
#pragma unroll
  for (int p = 0; p < 16; ++p) {
    int f = p * 256 + t;
    int row = f >> 5, c4 = (f & 31) * 4;
    *(float4*)&Big[row][c4] = *(const float4*)(vw + row * CC + c4);
  }
  __syncthreads();
  float p8[8];
#pragma unroll
  for (int i = 0; i < 8; ++i) p8[i] = 0.f;
  float csum = 0.f;
  const bool do_c0 = ((t & 15) == 0);
  for (int d = 0; d < CC; ++d) {
    float av = Al[tr][d];
    f32x4 w0 = *(const f32x4*)&Big[d][td8];
    f32x4 w1 = *(const f32x4*)&Big[d][td8 + 4];
    p8[0] += av * w0[0]; p8[1] += av * w0[1]; p8[2] += av * w0[2]; p8[3] += av * w0[3];
    p8[4] += av * w1[0]; p8[5] += av * w1[1]; p8[6] += av * w1[2]; p8[7] += av * w1[3];
    if (do_c0) csum += av * vb[d];
  }
  // pack to bf16 and store P row chunk
  u32x4 pk;
#pragma unroll
  for (int k = 0; k < 4; ++k)
    pk[k] = bf16rne(p8[2 * k]) | (bf16rne(p8[2 * k + 1]) << 16);
  *(u32x4*)(Pbf + (size_t)b * CC * CC + (size_t)(c0 + tr) * CC + td8) = pk;
  if (do_c0) c0v[b * CC + c0 + tr] = csum;
}

// ---------------------------------------------------------------------------
// K3 (MFMA): out[c][n] = sum_e P[c][e]*x[e][n] + x[c][n] + c0[c].
// Per block: one 64-n tile, all 128 c. X tile staged to LDS transposed as
// bf16 (swizzled); P staged as bf16 (swizzled). Residual re-read fp32 (L2).
// grid (256 n-tiles, 16 images), 4 waves.
// ---------------------------------------------------------------------------
__global__ __launch_bounds__(256, 3) void k3_mfma(const float* __restrict__ x,
    const unsigned short* __restrict__ Pbf, const float* __restrict__ c0v,
    float* __restrict__ out) {
  const int im = blockIdx.y;
  const int pb = im & 7;
  const int nb = blockIdx.x * 64;
  const float* X = x + (size_t)im * NFULL;
  float* O = out + (size_t)im * NFULL;
  __shared__ unsigned short Pl[128 * 128];   // swizzled: byte ^ ((c&15)<<4)
  __shared__ unsigned short XT[64 * 128];    // swizzled: byte ^ (((n>>2)&15)<<4)
  __shared__ float c0l[128];
  const int t = threadIdx.x;

  {  // P -> LDS (bf16 copy, swizzled)
    const unsigned short* Pg = Pbf + (size_t)pb * (CC * CC);
#pragma unroll
    for (int p = 0; p < 8; ++p) {
      int c = (t >> 4) + p * 16;
      int col = (t & 15) * 8;              // 8 bf16 = 16 B
      u32x4 v = *(const u32x4*)(Pg + c * CC + col);
      int off = (c * 256 + col * 2) ^ ((c & 15) << 4);
      *(u32x4*)((char*)Pl + off) = v;
    }
  }
  if (t < 128) c0l[t] = c0v[pb * CC + t];
  {  // X tile -> LDS transposed bf16
#pragma unroll
    for (int p = 0; p < 4; ++p) {
      int d0 = 2 * (t >> 4) + 32 * p;
      int n4 = (t & 15) * 4;
      f32x4 x0 = *(const f32x4*)(X + (size_t)d0 * NSP + nb + n4);
      f32x4 x1 = *(const f32x4*)(X + (size_t)(d0 + 1) * NSP + nb + n4);
#pragma unroll
      for (int i = 0; i < 4; ++i) {
        int n = n4 + i;
        unsigned pk = bf16rne(x0[i]) | (bf16rne(x1[i]) << 16);
        int off = (n * 256 + d0 * 2) ^ (((n >> 2) & 15) << 4);
        *(unsigned*)((char*)XT + off) = pk;
      }
    }
  }
  __syncthreads();

  const int w = t >> 6, l = t & 63;
  const int ln = l & 15, lg = l >> 4;
  const int n = nb + w * 16 + ln;
  s16x8 bf[4];
  {
    int row = w * 16 + ln;
    int sw = ((row >> 2) & 15) << 4;
#pragma unroll
    for (int kk = 0; kk < 4; ++kk)
      bf[kk] = *(const s16x8*)((char*)XT + ((row * 256 + kk * 64 + lg * 16) ^ sw));
  }
  f32x4 acc[8];
#pragma unroll
  for (int a = 0; a < 8; ++a) acc[a] = (f32x4){0.f, 0.f, 0.f, 0.f};
#pragma unroll
  for (int a = 0; a < 8; ++a) {
    int ca = a * 16 + ln;
    int sw = (ca & 15) << 4;
#pragma unroll
    for (int kk = 0; kk < 4; ++kk) {
      s16x8 af = *(const s16x8*)((char*)Pl + ((ca * 256 + kk * 64 + lg * 16) ^ sw));
      acc[a] = __builtin_amdgcn_mfma_f32_16x16x32_bf16(af, bf[kk], acc[a], 0, 0, 0);
    }
  }
#pragma unroll
  for (int a = 0; a < 8; ++a) {
#pragma unroll
    for (int r = 0; r < 4; ++r) {
      int c = a * 16 + lg * 4 + r;
      float xo = X[(size_t)c * NSP + n];
      O[(size_t)c * NSP + n] = acc[a][r] + xo + c0l[c];
    }
  }
}

// ---------------------------------------------------------------------------
extern "C" void kernel_launch(void* const* d_in, const int* in_sizes, int n_in,
                              void* d_out, int out_size, void* d_ws, size_t ws_size,
                              hipStream_t stream) {
  (void)in_sizes; (void)n_in; (void)out_size;
  const float* x  = (const float*)d_in[0];
  const float* qw = (const float*)d_in[1];
  const float* qb = (const float*)d_in[2];
  const float* kw = (const float*)d_in[3];
  const float* kb = (const float*)d_in[4];
  const float* vw = (const float*)d_in[5];
  const float* vb = (const float*)d_in[6];
  float* out = (float*)d_out;
  float* ws = (float*)d_ws;
  float* M   = ws;                       // 8*128*128
  float* rs  = M + 131072;               // 8*128
  float* rt  = rs + 1024;
  float* AST = rt + 1024;                // 8*128*128
  float* ATS = AST + 131072;
  unsigned short* Pbf = (unsigned short*)(ATS + 131072);  // 8*128*128 bf16
  float* c0v = ATS + 131072 + 65536;
  float* Mpart = c0v + 1024;
  const size_t base_floats = (size_t)(Mpart - ws);

  int NB, mode;
  if (ws_size >= (base_floats + (size_t)64 * 131072) * 4) { NB = 64; mode = 0; }
  else if (ws_size >= (base_floats + (size_t)32 * 131072) * 4) { NB = 32; mode = 0; }
  else { NB = 32; mode = 1; }
  const int nsteps = (16384 / NB) / 32;

  hipMemsetAsync(M, 0, (131072 + 2048) * sizeof(float), stream);  // M, rs, rt
  k1_mfma<<<dim3(NB, 8), 256, 0, stream>>>(x, mode ? M : Mpart, rs, rt, nsteps, mode);
  if (mode == 0) k1_reduce<<<512, 256, 0, stream>>>(Mpart, M, NB);
  k2ab<<<dim3(8, 8), 256, 0, stream>>>(M, qw, kw, qb, kb, rs, rt, AST, ATS);
  k2cd<<<dim3(8, 8), 256, 0, stream>>>(AST, ATS, vw, vb, Pbf, c0v);
  k3_mfma<<<dim3(256, 16), 256, 0, stream>>>(x, Pbf, c0v, out);
}

// Round 4
// 203.979 us; speedup vs baseline: 2.6634x; 1.0154x over previous
//
#include <hip/hip_runtime.h>

#define CC 128
#define NSP 16384              // 128*128 spatial
#define NFULL (CC * NSP)

typedef float f32x4 __attribute__((ext_vector_type(4)));
typedef short s16x8 __attribute__((ext_vector_type(8)));
typedef unsigned int u32x4 __attribute__((ext_vector_type(4)));

__device__ __forceinline__ unsigned bf16rne(float f) {
  unsigned u = __float_as_uint(f);
  return ((u + 0x7FFFu + ((u >> 16) & 1u)) >> 16) & 0xFFFFu;
}

// fp32[8] -> bf16 hi frag + bf16 lo frag (for K1 hi/lo split)
__device__ __forceinline__ void cvt8(const float* v, s16x8& hi, s16x8& lo) {
  unsigned ph[4], pl[4];
#pragma unroll
  for (int k = 0; k < 4; ++k) {
    unsigned u0 = __float_as_uint(v[2 * k]);
    unsigned u1 = __float_as_uint(v[2 * k + 1]);
    ph[k] = (u1 & 0xFFFF0000u) | (u0 >> 16);
    float h0 = __uint_as_float(u0 & 0xFFFF0000u);
    float h1 = __uint_as_float(u1 & 0xFFFF0000u);
    unsigned l0 = __float_as_uint(v[2 * k] - h0);
    unsigned l1 = __float_as_uint(v[2 * k + 1] - h1);
    pl[k] = (l1 & 0xFFFF0000u) | (l0 >> 16);
  }
  u32x4 H = {ph[0], ph[1], ph[2], ph[3]};
  u32x4 L = {pl[0], pl[1], pl[2], pl[3]};
  hi = __builtin_bit_cast(s16x8, H);
  lo = __builtin_bit_cast(s16x8, L);
}

// zero M/rs/rt (mode-1 fallback only; replaces the 78us rocclr fill kernel)
__global__ __launch_bounds__(256) void zerok(float* __restrict__ p, int n) {
  int i = blockIdx.x * 256 + threadIdx.x;
  if (i < n) p[i] = 0.f;
}

// ---------------------------------------------------------------------------
// K1 (MFMA): per batch b, chunk: partial Xt*Xs^T over n-chunk (hi/lo split).
// mode 0: atomic-free — partial M to Mdst[(chunk*8+b)*16384+..], partial row
// sums to rtpart/rspart[(chunk*8+b)*128+..]. mode 1: atomics into M/rs/rt.
// ---------------------------------------------------------------------------
__global__ __launch_bounds__(256, 2) void k1_mfma(const float* __restrict__ x,
    float* __restrict__ Mdst, float* __restrict__ rs, float* __restrict__ rt,
    float* __restrict__ rspart, float* __restrict__ rtpart,
    int nsteps, int mode) {
  const int b = blockIdx.y;
  const int chunk = blockIdx.x;
  const int n0 = chunk * (nsteps * 32);
  const int t = threadIdx.x;
  const int w = t >> 6, l = t & 63;
  const int wr = w >> 1, wc = w & 1;
  const int lr = l & 15;
  const int lk = (l >> 4) << 3;
  const float* Xs = x + (size_t)b * NFULL;
  const float* Xt = x + (size_t)(b + 8) * NFULL;
  const float* Ab = Xt + (size_t)(wr * 64 + lr) * NSP + n0 + lk;
  const float* Bb = Xs + (size_t)(wc * 64 + lr) * NSP + n0 + lk;

  f32x4 acc[4][4];
#pragma unroll
  for (int a = 0; a < 4; ++a)
#pragma unroll
    for (int bb = 0; bb < 4; ++bb) acc[a][bb] = (f32x4){0.f, 0.f, 0.f, 0.f};
  float rtp[4] = {0.f, 0.f, 0.f, 0.f};
  float rsp[4] = {0.f, 0.f, 0.f, 0.f};

  for (int s = 0; s < nsteps; ++s) {
    const float* ap = Ab + s * 32;
    const float* bp = Bb + s * 32;
    s16x8 ahi[4], alo[4], bhi[4], blo[4];
    {
      float ar[4][8];
#pragma unroll
      for (int a = 0; a < 4; ++a) {
        *(f32x4*)&ar[a][0] = *(const f32x4*)(ap + (size_t)a * 16 * NSP);
        *(f32x4*)&ar[a][4] = *(const f32x4*)(ap + (size_t)a * 16 * NSP + 4);
      }
      if (wc == 0) {
#pragma unroll
        for (int a = 0; a < 4; ++a) {
          float s0 = (ar[a][0] + ar[a][1]) + (ar[a][2] + ar[a][3]);
          float s1 = (ar[a][4] + ar[a][5]) + (ar[a][6] + ar[a][7]);
          rtp[a] += s0 + s1;
        }
      }
#pragma unroll
      for (int a = 0; a < 4; ++a) cvt8(ar[a], ahi[a], alo[a]);
    }
    {
      float br[4][8];
#pragma unroll
      for (int bb = 0; bb < 4; ++bb) {
        *(f32x4*)&br[bb][0] = *(const f32x4*)(bp + (size_t)bb * 16 * NSP);
        *(f32x4*)&br[bb][4] = *(const f32x4*)(bp + (size_t)bb * 16 * NSP + 4);
      }
      if (wr == 0) {
#pragma unroll
        for (int bb = 0; bb < 4; ++bb) {
          float s0 = (br[bb][0] + br[bb][1]) + (br[bb][2] + br[bb][3]);
          float s1 = (br[bb][4] + br[bb][5]) + (br[bb][6] + br[bb][7]);
          rsp[bb] += s0 + s1;
        }
      }
#pragma unroll
      for (int bb = 0; bb < 4; ++bb) cvt8(br[bb], bhi[bb], blo[bb]);
    }
#pragma unroll
    for (int a = 0; a < 4; ++a)
#pragma unroll
      for (int bb = 0; bb < 4; ++bb) {
        acc[a][bb] = __builtin_amdgcn_mfma_f32_16x16x32_bf16(ahi[a], bhi[bb], acc[a][bb], 0, 0, 0);
        acc[a][bb] = __builtin_amdgcn_mfma_f32_16x16x32_bf16(ahi[a], blo[bb], acc[a][bb], 0, 0, 0);
        acc[a][bb] = __builtin_amdgcn_mfma_f32_16x16x32_bf16(alo[a], bhi[bb], acc[a][bb], 0, 0, 0);
      }
  }

  // reduce row sums across the 4 k-groups (lanes l, l^16, l^32, l^48)
  if (wc == 0) {
#pragma unroll
    for (int a = 0; a < 4; ++a) {
      float v = rtp[a];
      v += __shfl_xor(v, 16);
      v += __shfl_xor(v, 32);
      if (l < 16) {
        int i = wr * 64 + a * 16 + l;
        if (mode == 0) rtpart[((size_t)chunk * 8 + b) * CC + i] = v;
        else atomicAdd(&rt[b * CC + i], v);
      }
    }
  }
  if (wr == 0) {
#pragma unroll
    for (int bb = 0; bb < 4; ++bb) {
      float v = rsp[bb];
      v += __shfl_xor(v, 16);
      v += __shfl_xor(v, 32);
      if (l < 16) {
        int j = wc * 64 + bb * 16 + l;
        if (mode == 0) rspart[((size_t)chunk * 8 + b) * CC + j] = v;
        else atomicAdd(&rs[b * CC + j], v);
      }
    }
  }

  const int rquad = (l >> 4) << 2;
  if (mode == 0) {
    float* Mp = Mdst + ((size_t)chunk * 8 + b) * (CC * CC);
#pragma unroll
    for (int a = 0; a < 4; ++a)
#pragma unroll
      for (int bb = 0; bb < 4; ++bb)
#pragma unroll
        for (int r = 0; r < 4; ++r) {
          int i = wr * 64 + a * 16 + rquad + r;
          int j = wc * 64 + bb * 16 + lr;
          Mp[i * CC + j] = acc[a][bb][r];
        }
  } else {
    float* Mp = Mdst + (size_t)b * (CC * CC);
#pragma unroll
    for (int a = 0; a < 4; ++a)
#pragma unroll
      for (int bb = 0; bb < 4; ++bb)
#pragma unroll
        for (int r = 0; r < 4; ++r) {
          int i = wr * 64 + a * 16 + rquad + r;
          int j = wc * 64 + bb * 16 + lr;
          atomicAdd(&Mp[i * CC + j], acc[a][bb][r]);
        }
  }
}

// Sum partials. Blocks [0,512): M. Blocks [512,520): rt then rs.
__global__ __launch_bounds__(256) void k1_reduce(const float* __restrict__ Mpart,
    const float* __restrict__ rspart, const float* __restrict__ rtpart,
    float* __restrict__ M, float* __restrict__ rs, float* __restrict__ rt,
    int NB) {
  if (blockIdx.x < 512) {
    const int idx = blockIdx.x * 256 + threadIdx.x;      // < 131072
    const int b = idx >> 14, e = idx & 16383;
    float s = 0.f;
    for (int c = 0; c < NB; ++c) s += Mpart[((size_t)c * 8 + b) * (CC * CC) + e];
    M[idx] = s;
  } else {
    const int v = (blockIdx.x - 512) * 256 + threadIdx.x;  // < 2048
    if (v < 1024) {
      float s = 0.f;
      for (int c = 0; c < NB; ++c) s += rtpart[(size_t)c * 1024 + v];
      rt[v] = s;
    } else {
      const int u = v - 1024;
      float s = 0.f;
      for (int c = 0; c < NB; ++c) s += rspart[(size_t)c * 1024 + u];
      rs[u] = s;
    }
  }
}

// ---------------------------------------------------------------------------
// K2ab fused: T1=Wq*M, T2=Wq*M^T (kept in LDS), us/ut, then G + softmax for
// both 'st' (which=0) and 'ts' (which=1). grid (8 c-groups, 8 b).
// ---------------------------------------------------------------------------
__global__ __launch_bounds__(256) void k2ab(const float* __restrict__ M,
    const float* __restrict__ qw, const float* __restrict__ kw,
    const float* __restrict__ qb, const float* __restrict__ kb,
    const float* __restrict__ rs, const float* __restrict__ rt,
    float* __restrict__ Ast, float* __restrict__ Ats) {
  const int b = blockIdx.y;
  const int c0 = blockIdx.x * 16;
  __shared__ float Big[128][129];      // M, later Wk
  __shared__ float Wq[16][128];
  __shared__ float T12[2][16][128];    // [0]=T1 rows, [1]=T2 rows
  __shared__ float uvv[2][16];         // [0]=ut (st), [1]=us (ts)
  __shared__ float wv2[2][128];        // [0]=Wk*rs (st), [1]=Wk*rt (ts)
  const int t = threadIdx.x;
  const float* Mb = M + (size_t)b * CC * CC;
#pragma unroll
  for (int p = 0; p < 16; ++p) {
    int f = p * 256 + t;
    int row = f >> 5, c4 = (f & 31) * 4;
    float4 v = *(const float4*)(Mb + row * CC + c4);
    Big[row][c4 + 0] = v.x; Big[row][c4 + 1] = v.y;
    Big[row][c4 + 2] = v.z; Big[row][c4 + 3] = v.w;
  }
#pragma unroll
  for (int p = 0; p < 2; ++p) {
    int f = p * 256 + t;
    int row = f >> 5, c4 = (f & 31) * 4;
    *(float4*)&Wq[row][c4] = *(const float4*)(qw + (c0 + row) * CC + c4);
  }
  __syncthreads();
  if (t < 32) {
    int c = t & 15;
    const float* r = (t < 16) ? rs : rt;
    float s = 0.f;
    for (int i = 0; i < CC; ++i) s += Wq[c][i] * r[b * CC + i];
    uvv[(t < 16) ? 1 : 0][c] = s;      // us->[1], ut->[0]
  }
  const int tr = t >> 4;
  const int td8 = (t & 15) * 8;
  {
    float a1[8], a2[8];
#pragma unroll
    for (int j = 0; j < 8; ++j) { a1[j] = 0.f; a2[j] = 0.f; }
    for (int i = 0; i < CC; ++i) {
      float wq = Wq[tr][i];
#pragma unroll
      for (int j = 0; j < 8; ++j) {
        a1[j] += wq * Big[i][td8 + j];
        a2[j] += wq * Big[td8 + j][i];
      }
    }
#pragma unroll
    for (int j = 0; j < 8; ++j) { T12[0][tr][td8 + j] = a1[j]; T12[1][tr][td8 + j] = a2[j]; }
  }
  __syncthreads();
  // overwrite Big with Wk
#pragma unroll
  for (int p = 0; p < 16; ++p) {
    int f = p * 256 + t;
    int row = f >> 5, c4 = (f & 31) * 4;
    float4 v = *(const float4*)(kw + row * CC + c4);
    Big[row][c4 + 0] = v.x; Big[row][c4 + 1] = v.y;
    Big[row][c4 + 2] = v.z; Big[row][c4 + 3] = v.w;
  }
  __syncthreads();
  {
    int d = t & 127;
    int wh = t >> 7;                   // 0: rs, 1: rt
    const float* r = (wh ? rt : rs) + b * CC;
    float s = 0.f;
    for (int j = 0; j < CC; ++j) s += Big[d][j] * r[j];
    wv2[wh][d] = s;
  }
  __syncthreads();
  const int c = c0 + tr;
  const float bqc = qb[c];
#pragma unroll 1
  for (int which = 0; which < 2; ++which) {
    float g[8];
#pragma unroll
    for (int dd = 0; dd < 8; ++dd) {
      int d = td8 + dd;
      g[dd] = uvv[which][tr] * kb[d] + bqc * wv2[which][d] + 16384.f * bqc * kb[d];
    }
    for (int j = 0; j < CC; ++j) {
      float tv = T12[which][tr][j];
#pragma unroll
      for (int dd = 0; dd < 8; ++dd) g[dd] += tv * Big[td8 + dd][j];
    }
    float m = g[0];
#pragma unroll
    for (int dd = 1; dd < 8; ++dd) m = fmaxf(m, g[dd]);
#pragma unroll
    for (int off = 1; off < 16; off <<= 1) m = fmaxf(m, __shfl_xor(m, off));
    float s = 0.f;
#pragma unroll
    for (int dd = 0; dd < 8; ++dd) { g[dd] = expf(g[dd] - m); s += g[dd]; }
#pragma unroll
    for (int off = 1; off < 16; off <<= 1) s += __shfl_xor(s, off);
    const float inv = 1.f / s;
    float* A = (which ? Ats : Ast) + (size_t)b * CC * CC + (size_t)c * CC;
#pragma unroll
    for (int dd = 0; dd < 8; ++dd) A[td8 + dd] = g[dd] * inv;
  }
}

// ---------------------------------------------------------------------------
// K2cd fused: L = Ast*Ats^T, softmax -> Att (LDS), then P = Att*Wv (-> bf16),
// c0 = Att*bv.  grid (8 c-groups, 8 b).
// ---------------------------------------------------------------------------
__global__ __launch_bounds__(256) void k2cd(const float* __restrict__ Ast,
    const float* __restrict__ Ats, const float* __restrict__ vw,
    const float* __restrict__ vb, unsigned short* __restrict__ Pbf,
    float* __restrict__ c0v) {
  const int b = blockIdx.y;
  const int c0 = blockIdx.x * 16;
  __shared__ float Big[128][132];      // Ats, later Wv[d][i]
  __shared__ float Tl[16][128];        // Ast rows
  __shared__ float Al[16][128];        // Att rows
  const int t = threadIdx.x;
  const float* Bb = Ats + (size_t)b * CC * CC;
  const float* Tb = Ast + (size_t)b * CC * CC;
#pragma unroll
  for (int p = 0; p < 16; ++p) {
    int f = p * 256 + t;
    int row = f >> 5, c4 = (f & 31) * 4;
    *(float4*)&Big[row][c4] = *(const float4*)(Bb + row * CC + c4);
  }
#pragma unroll
  for (int p = 0; p < 2; ++p) {
    int f = p * 256 + t;
    int row = f >> 5, c4 = (f & 31) * 4;
    *(float4*)&Tl[row][c4] = *(const float4*)(Tb + (c0 + row) * CC + c4);
  }
  __syncthreads();
  const int tr = t >> 4;
  const int td8 = (t & 15) * 8;
  {
    float g[8];
#pragma unroll
    for (int dd = 0; dd < 8; ++dd) g[dd] = 0.f;
    for (int e = 0; e < CC; ++e) {
      float tv = Tl[tr][e];
#pragma unroll
      for (int dd = 0; dd < 8; ++dd) g[dd] += tv * Big[td8 + dd][e];
    }
    float m = g[0];
#pragma unroll
    for (int dd = 1; dd < 8; ++dd) m = fmaxf(m, g[dd]);
#pragma unroll
    for (int off = 1; off < 16; off <<= 1) m = fmaxf(m, __shfl_xor(m, off));
    float s = 0.f;
#pragma unroll
    for (int dd = 0; dd < 8; ++dd) { g[dd] = expf(g[dd] - m); s += g[dd]; }
#pragma unroll
    for (int off = 1; off < 16; off <<= 1) s += __shfl_xor(s, off);
    const float inv = 1.f / s;
#pragma unroll
    for (int dd = 0; dd < 8; ++dd) Al[tr][td8 + dd] = g[dd] * inv;
  }
  __syncthreads();
  // overwrite Big with Wv[d][i]
#pragma unroll
  for (int p = 0; p < 16; ++p) {
    int f = p * 256 + t;
    int row = f >> 5, c4 = (f & 31) * 4;
    *(float4*)&Big[row][c4] = *(const float4*)(vw + row * CC + c4);
  }
  __syncthreads();
  float p8[8];
#pragma unroll
  for (int i = 0; i < 8; ++i) p8[i] = 0.f;
  float csum = 0.f;
  const bool do_c0 = ((t & 15) == 0);
  for (int d = 0; d < CC; ++d) {
    float av = Al[tr][d];
    f32x4 w0 = *(const f32x4*)&Big[d][td8];
    f32x4 w1 = *(const f32x4*)&Big[d][td8 + 4];
    p8[0] += av * w0[0]; p8[1] += av * w0[1]; p8[2] += av * w0[2]; p8[3] += av * w0[3];
    p8[4] += av * w1[0]; p8[5] += av * w1[1]; p8[6] += av * w1[2]; p8[7] += av * w1[3];
    if (do_c0) csum += av * vb[d];
  }
  u32x4 pk;
#pragma unroll
  for (int k = 0; k < 4; ++k)
    pk[k] = bf16rne(p8[2 * k]) | (bf16rne(p8[2 * k + 1]) << 16);
  *(u32x4*)(Pbf + (size_t)b * CC * CC + (size_t)(c0 + tr) * CC + td8) = pk;
  if (do_c0) c0v[b * CC + c0 + tr] = csum;
}

// ---------------------------------------------------------------------------
// K3 (MFMA): out[c][n] = sum_e P[c][e]*x[e][n] + x[c][n] + c0[c].
// grid (256 n-tiles, 16 images), 4 waves.
// ---------------------------------------------------------------------------
__global__ __launch_bounds__(256, 3) void k3_mfma(const float* __restrict__ x,
    const unsigned short* __restrict__ Pbf, const float* __restrict__ c0v,
    float* __restrict__ out) {
  const int im = blockIdx.y;
  const int pb = im & 7;
  const int nb = blockIdx.x * 64;
  const float* X = x + (size_t)im * NFULL;
  float* O = out + (size_t)im * NFULL;
  __shared__ unsigned short Pl[128 * 128];   // swizzled: byte ^ ((c&15)<<4)
  __shared__ unsigned short XT[64 * 128];    // swizzled: byte ^ (((n>>2)&15)<<4)
  __shared__ float c0l[128];
  const int t = threadIdx.x;

  {  // P -> LDS (bf16 copy, swizzled)
    const unsigned short* Pg = Pbf + (size_t)pb * (CC * CC);
#pragma unroll
    for (int p = 0; p < 8; ++p) {
      int c = (t >> 4) + p * 16;
      int col = (t & 15) * 8;              // 8 bf16 = 16 B
      u32x4 v = *(const u32x4*)(Pg + c * CC + col);
      int off = (c * 256 + col * 2) ^ ((c & 15) << 4);
      *(u32x4*)((char*)Pl + off) = v;
    }
  }
  if (t < 128) c0l[t] = c0v[pb * CC + t];
  {  // X tile -> LDS transposed bf16
#pragma unroll
    for (int p = 0; p < 4; ++p) {
      int d0 = 2 * (t >> 4) + 32 * p;
      int n4 = (t & 15) * 4;
      f32x4 x0 = *(const f32x4*)(X + (size_t)d0 * NSP + nb + n4);
      f32x4 x1 = *(const f32x4*)(X + (size_t)(d0 + 1) * NSP + nb + n4);
#pragma unroll
      for (int i = 0; i < 4; ++i) {
        int n = n4 + i;
        unsigned pk = bf16rne(x0[i]) | (bf16rne(x1[i]) << 16);
        int off = (n * 256 + d0 * 2) ^ (((n >> 2) & 15) << 4);
        *(unsigned*)((char*)XT + off) = pk;
      }
    }
  }
  __syncthreads();

  const int w = t >> 6, l = t & 63;
  const int ln = l & 15, lg = l >> 4;
  const int n = nb + w * 16 + ln;
  s16x8 bf[4];
  {
    int row = w * 16 + ln;
    int sw = ((row >> 2) & 15) << 4;
#pragma unroll
    for (int kk = 0; kk < 4; ++kk)
      bf[kk] = *(const s16x8*)((char*)XT + ((row * 256 + kk * 64 + lg * 16) ^ sw));
  }
  f32x4 acc[8];
#pragma unroll
  for (int a = 0; a < 8; ++a) acc[a] = (f32x4){0.f, 0.f, 0.f, 0.f};
#pragma unroll
  for (int a = 0; a < 8; ++a) {
    int ca = a * 16 + ln;
    int sw = (ca & 15) << 4;
#pragma unroll
    for (int kk = 0; kk < 4; ++kk) {
      s16x8 af = *(const s16x8*)((char*)Pl + ((ca * 256 + kk * 64 + lg * 16) ^ sw));
      acc[a] = __builtin_amdgcn_mfma_f32_16x16x32_bf16(af, bf[kk], acc[a], 0, 0, 0);
    }
  }
#pragma unroll
  for (int a = 0; a < 8; ++a) {
#pragma unroll
    for (int r = 0; r < 4; ++r) {
      int c = a * 16 + lg * 4 + r;
      float xo = X[(size_t)c * NSP + n];
      O[(size_t)c * NSP + n] = acc[a][r] + xo + c0l[c];
    }
  }
}

// ---------------------------------------------------------------------------
extern "C" void kernel_launch(void* const* d_in, const int* in_sizes, int n_in,
                              void* d_out, int out_size, void* d_ws, size_t ws_size,
                              hipStream_t stream) {
  (void)in_sizes; (void)n_in; (void)out_size;
  const float* x  = (const float*)d_in[0];
  const float* qw = (const float*)d_in[1];
  const float* qb = (const float*)d_in[2];
  const float* kw = (const float*)d_in[3];
  const float* kb = (const float*)d_in[4];
  const float* vw = (const float*)d_in[5];
  const float* vb = (const float*)d_in[6];
  float* out = (float*)d_out;
  float* ws = (float*)d_ws;
  float* M   = ws;                       // 8*128*128  (M, rs, rt contiguous)
  float* rs  = M + 131072;               // 8*128
  float* rt  = rs + 1024;
  float* AST = rt + 1024;                // 8*128*128
  float* ATS = AST + 131072;
  unsigned short* Pbf = (unsigned short*)(ATS + 131072);  // 8*128*128 bf16
  float* c0v = ATS + 131072 + 65536;
  float* Mpart = c0v + 1024;
  const size_t base_floats = (size_t)(Mpart - ws);

  int NB, mode;
  if (ws_size >= (base_floats + (size_t)64 * (131072 + 2048)) * 4) { NB = 64; mode = 0; }
  else if (ws_size >= (base_floats + (size_t)32 * (131072 + 2048)) * 4) { NB = 32; mode = 0; }
  else { NB = 32; mode = 1; }
  const int nsteps = (16384 / NB) / 32;
  float* rtpart = Mpart + (size_t)NB * 131072;   // NB*8*128
  float* rspart = rtpart + (size_t)NB * 1024;    // NB*8*128

  if (mode == 1) zerok<<<(133120 + 255) / 256, 256, 0, stream>>>(M, 133120);
  k1_mfma<<<dim3(NB, 8), 256, 0, stream>>>(x, mode ? M : Mpart, rs, rt,
                                           rspart, rtpart, nsteps, mode);
  if (mode == 0)
    k1_reduce<<<520, 256, 0, stream>>>(Mpart, rspart, rtpart, M, rs, rt, NB);
  k2ab<<<dim3(8, 8), 256, 0, stream>>>(M, qw, kw, qb, kb, rs, rt, AST, ATS);
  k2cd<<<dim3(8, 8), 256, 0, stream>>>(AST, ATS, vw, vb, Pbf, c0v);
  k3_mfma<<<dim3(256, 16), 256, 0, stream>>>(x, Pbf, c0v, out);
}

// Round 5
// 200.797 us; speedup vs baseline: 2.7056x; 1.0158x over previous
//
#include <hip/hip_runtime.h>

#define CC 128
#define NSP 16384              // 128*128 spatial
#define NFULL (CC * NSP)

typedef float f32x4 __attribute__((ext_vector_type(4)));
typedef short s16x8 __attribute__((ext_vector_type(8)));
typedef unsigned int u32x4 __attribute__((ext_vector_type(4)));

__device__ __forceinline__ unsigned bf16rne(float f) {
  unsigned u = __float_as_uint(f);
  return ((u + 0x7FFFu + ((u >> 16) & 1u)) >> 16) & 0xFFFFu;
}

// fp32[8] -> bf16 hi frag + bf16 lo frag (for K1 hi/lo split)
__device__ __forceinline__ void cvt8(const float* v, s16x8& hi, s16x8& lo) {
  unsigned ph[4], pl[4];
#pragma unroll
  for (int k = 0; k < 4; ++k) {
    unsigned u0 = __float_as_uint(v[2 * k]);
    unsigned u1 = __float_as_uint(v[2 * k + 1]);
    ph[k] = (u1 & 0xFFFF0000u) | (u0 >> 16);
    float h0 = __uint_as_float(u0 & 0xFFFF0000u);
    float h1 = __uint_as_float(u1 & 0xFFFF0000u);
    unsigned l0 = __float_as_uint(v[2 * k] - h0);
    unsigned l1 = __float_as_uint(v[2 * k + 1] - h1);
    pl[k] = (l1 & 0xFFFF0000u) | (l0 >> 16);
  }
  u32x4 H = {ph[0], ph[1], ph[2], ph[3]};
  u32x4 L = {pl[0], pl[1], pl[2], pl[3]};
  hi = __builtin_bit_cast(s16x8, H);
  lo = __builtin_bit_cast(s16x8, L);
}

// zero M/rs/rt (mode-1 fallback only)
__global__ __launch_bounds__(256) void zerok(float* __restrict__ p, int n) {
  int i = blockIdx.x * 256 + threadIdx.x;
  if (i < n) p[i] = 0.f;
}

// ---------------------------------------------------------------------------
// K1 (MFMA): per batch b, chunk: partial Xt*Xs^T over n-chunk (hi/lo split).
// ---------------------------------------------------------------------------
__global__ __launch_bounds__(256, 2) void k1_mfma(const float* __restrict__ x,
    float* __restrict__ Mdst, float* __restrict__ rs, float* __restrict__ rt,
    float* __restrict__ rspart, float* __restrict__ rtpart,
    int nsteps, int mode) {
  const int b = blockIdx.y;
  const int chunk = blockIdx.x;
  const int n0 = chunk * (nsteps * 32);
  const int t = threadIdx.x;
  const int w = t >> 6, l = t & 63;
  const int wr = w >> 1, wc = w & 1;
  const int lr = l & 15;
  const int lk = (l >> 4) << 3;
  const float* Xs = x + (size_t)b * NFULL;
  const float* Xt = x + (size_t)(b + 8) * NFULL;
  const float* Ab = Xt + (size_t)(wr * 64 + lr) * NSP + n0 + lk;
  const float* Bb = Xs + (size_t)(wc * 64 + lr) * NSP + n0 + lk;

  f32x4 acc[4][4];
#pragma unroll
  for (int a = 0; a < 4; ++a)
#pragma unroll
    for (int bb = 0; bb < 4; ++bb) acc[a][bb] = (f32x4){0.f, 0.f, 0.f, 0.f};
  float rtp[4] = {0.f, 0.f, 0.f, 0.f};
  float rsp[4] = {0.f, 0.f, 0.f, 0.f};

  for (int s = 0; s < nsteps; ++s) {
    const float* ap = Ab + s * 32;
    const float* bp = Bb + s * 32;
    s16x8 ahi[4], alo[4], bhi[4], blo[4];
    {
      float ar[4][8];
#pragma unroll
      for (int a = 0; a < 4; ++a) {
        *(f32x4*)&ar[a][0] = *(const f32x4*)(ap + (size_t)a * 16 * NSP);
        *(f32x4*)&ar[a][4] = *(const f32x4*)(ap + (size_t)a * 16 * NSP + 4);
      }
      if (wc == 0) {
#pragma unroll
        for (int a = 0; a < 4; ++a) {
          float s0 = (ar[a][0] + ar[a][1]) + (ar[a][2] + ar[a][3]);
          float s1 = (ar[a][4] + ar[a][5]) + (ar[a][6] + ar[a][7]);
          rtp[a] += s0 + s1;
        }
      }
#pragma unroll
      for (int a = 0; a < 4; ++a) cvt8(ar[a], ahi[a], alo[a]);
    }
    {
      float br[4][8];
#pragma unroll
      for (int bb = 0; bb < 4; ++bb) {
        *(f32x4*)&br[bb][0] = *(const f32x4*)(bp + (size_t)bb * 16 * NSP);
        *(f32x4*)&br[bb][4] = *(const f32x4*)(bp + (size_t)bb * 16 * NSP + 4);
      }
      if (wr == 0) {
#pragma unroll
        for (int bb = 0; bb < 4; ++bb) {
          float s0 = (br[bb][0] + br[bb][1]) + (br[bb][2] + br[bb][3]);
          float s1 = (br[bb][4] + br[bb][5]) + (br[bb][6] + br[bb][7]);
          rsp[bb] += s0 + s1;
        }
      }
#pragma unroll
      for (int bb = 0; bb < 4; ++bb) cvt8(br[bb], bhi[bb], blo[bb]);
    }
#pragma unroll
    for (int a = 0; a < 4; ++a)
#pragma unroll
      for (int bb = 0; bb < 4; ++bb) {
        acc[a][bb] = __builtin_amdgcn_mfma_f32_16x16x32_bf16(ahi[a], bhi[bb], acc[a][bb], 0, 0, 0);
        acc[a][bb] = __builtin_amdgcn_mfma_f32_16x16x32_bf16(ahi[a], blo[bb], acc[a][bb], 0, 0, 0);
        acc[a][bb] = __builtin_amdgcn_mfma_f32_16x16x32_bf16(alo[a], bhi[bb], acc[a][bb], 0, 0, 0);
      }
  }

  if (wc == 0) {
#pragma unroll
    for (int a = 0; a < 4; ++a) {
      float v = rtp[a];
      v += __shfl_xor(v, 16);
      v += __shfl_xor(v, 32);
      if (l < 16) {
        int i = wr * 64 + a * 16 + l;
        if (mode == 0) rtpart[((size_t)chunk * 8 + b) * CC + i] = v;
        else atomicAdd(&rt[b * CC + i], v);
      }
    }
  }
  if (wr == 0) {
#pragma unroll
    for (int bb = 0; bb < 4; ++bb) {
      float v = rsp[bb];
      v += __shfl_xor(v, 16);
      v += __shfl_xor(v, 32);
      if (l < 16) {
        int j = wc * 64 + bb * 16 + l;
        if (mode == 0) rspart[((size_t)chunk * 8 + b) * CC + j] = v;
        else atomicAdd(&rs[b * CC + j], v);
      }
    }
  }

  const int rquad = (l >> 4) << 2;
  if (mode == 0) {
    float* Mp = Mdst + ((size_t)chunk * 8 + b) * (CC * CC);
#pragma unroll
    for (int a = 0; a < 4; ++a)
#pragma unroll
      for (int bb = 0; bb < 4; ++bb)
#pragma unroll
        for (int r = 0; r < 4; ++r) {
          int i = wr * 64 + a * 16 + rquad + r;
          int j = wc * 64 + bb * 16 + lr;
          Mp[i * CC + j] = acc[a][bb][r];
        }
  } else {
    float* Mp = Mdst + (size_t)b * (CC * CC);
#pragma unroll
    for (int a = 0; a < 4; ++a)
#pragma unroll
      for (int bb = 0; bb < 4; ++bb)
#pragma unroll
        for (int r = 0; r < 4; ++r) {
          int i = wr * 64 + a * 16 + rquad + r;
          int j = wc * 64 + bb * 16 + lr;
          atomicAdd(&Mp[i * CC + j], acc[a][bb][r]);
        }
  }
}

// Sum partials, vectorized. Blocks [0,128): M. Block 128: rt. Block 129: rs.
__global__ __launch_bounds__(256) void k1_reduce(const float* __restrict__ Mpart,
    const float* __restrict__ rspart, const float* __restrict__ rtpart,
    float* __restrict__ M, float* __restrict__ rs, float* __restrict__ rt,
    int NB) {
  const int t = threadIdx.x;
  if (blockIdx.x < 128) {
    const int i4 = blockIdx.x * 256 + t;     // < 32768
    const int b = i4 >> 12;
    const int e = (i4 & 4095) * 4;
    f32x4 s = (f32x4){0.f, 0.f, 0.f, 0.f};
    for (int c = 0; c < NB; ++c) {
      f32x4 v = *(const f32x4*)(Mpart + ((size_t)c * 8 + b) * (CC * CC) + e);
      s += v;
    }
    *(f32x4*)(M + (size_t)b * CC * CC + e) = s;
  } else if (blockIdx.x == 128) {
    const int e = t * 4;                      // < 1024
    f32x4 s = (f32x4){0.f, 0.f, 0.f, 0.f};
    for (int c = 0; c < NB; ++c) s += *(const f32x4*)(rtpart + (size_t)c * 1024 + e);
    *(f32x4*)(rt + e) = s;
  } else {
    const int e = t * 4;
    f32x4 s = (f32x4){0.f, 0.f, 0.f, 0.f};
    for (int c = 0; c < NB; ++c) s += *(const f32x4*)(rspart + (size_t)c * 1024 + e);
    *(f32x4*)(rs + e) = s;
  }
}

// ---------------------------------------------------------------------------
// K2ab fused: T1=Wq*M, T2=Wq*M^T, us/ut, G + softmax (st & ts).
// grid (16 c-groups of 8 rows, 8 b). Cols strided: lane L owns {L+32j}.
// ---------------------------------------------------------------------------
__global__ __launch_bounds__(256) void k2ab(const float* __restrict__ M,
    const float* __restrict__ qw, const float* __restrict__ kw,
    const float* __restrict__ qb, const float* __restrict__ kb,
    const float* __restrict__ rs, const float* __restrict__ rt,
    float* __restrict__ Ast, float* __restrict__ Ats) {
  const int b = blockIdx.y;
  const int c0 = blockIdx.x * 8;
  __shared__ float Big[128][132];      // M, later Wk (132: 16B-aligned rows)
  __shared__ float Wq[8][128];
  __shared__ float T12[2][8][128];
  __shared__ float uvv[2][8];
  __shared__ float wv2[2][128];
  const int t = threadIdx.x;
  const float* Mb = M + (size_t)b * CC * CC;
#pragma unroll
  for (int p = 0; p < 16; ++p) {
    int f = p * 256 + t;
    int row = f >> 5, c4 = (f & 31) * 4;
    *(f32x4*)&Big[row][c4] = *(const f32x4*)(Mb + row * CC + c4);
  }
  { int row = t >> 5, c4 = (t & 31) * 4;
    *(f32x4*)&Wq[row][c4] = *(const f32x4*)(qw + (c0 + row) * CC + c4); }
  __syncthreads();
  if (t < 16) {
    int c = t & 7;
    const float* r = ((t < 8) ? rs : rt) + b * CC;
    float s = 0.f;
    for (int i = 0; i < CC; ++i) s += Wq[c][i] * r[i];
    uvv[(t < 8) ? 1 : 0][c] = s;       // us->[1], ut->[0]
  }
  const int tr = t >> 5;               // row 0..7
  const int L = t & 31;                // col lane
  {
    float a1[4] = {0.f, 0.f, 0.f, 0.f}, a2[4] = {0.f, 0.f, 0.f, 0.f};
    for (int i = 0; i < CC; ++i) {
      float wq = Wq[tr][i];
#pragma unroll
      for (int j = 0; j < 4; ++j) a1[j] += wq * Big[i][L + 32 * j];
    }
    for (int i4 = 0; i4 < 32; ++i4) {
      f32x4 wq4 = *(const f32x4*)&Wq[tr][i4 * 4];
#pragma unroll
      for (int j = 0; j < 4; ++j) {
        f32x4 m4 = *(const f32x4*)&Big[L + 32 * j][i4 * 4];
        a2[j] += wq4[0]*m4[0] + wq4[1]*m4[1] + wq4[2]*m4[2] + wq4[3]*m4[3];
      }
    }
#pragma unroll
    for (int j = 0; j < 4; ++j) {
      T12[0][tr][L + 32 * j] = a1[j];
      T12[1][tr][L + 32 * j] = a2[j];
    }
  }
  __syncthreads();
  // overwrite Big with Wk
#pragma unroll
  for (int p = 0; p < 16; ++p) {
    int f = p * 256 + t;
    int row = f >> 5, c4 = (f & 31) * 4;
    *(f32x4*)&Big[row][c4] = *(const f32x4*)(kw + row * CC + c4);
  }
  __syncthreads();
  {
    int d = t & 127, wh = t >> 7;      // 0: rs, 1: rt
    const float* r = (wh ? rt : rs) + b * CC;
    float s = 0.f;
    for (int i4 = 0; i4 < 32; ++i4) {
      f32x4 w4 = *(const f32x4*)&Big[d][i4 * 4];
      s += w4[0]*r[i4*4] + w4[1]*r[i4*4+1] + w4[2]*r[i4*4+2] + w4[3]*r[i4*4+3];
    }
    wv2[wh][d] = s;
  }
  __syncthreads();
  const int c = c0 + tr;
  const float bqc = qb[c];
#pragma unroll 1
  for (int which = 0; which < 2; ++which) {
    float g[4];
#pragma unroll
    for (int j = 0; j < 4; ++j) {
      int d = L + 32 * j;
      g[j] = uvv[which][tr] * kb[d] + bqc * wv2[which][d] + 16384.f * bqc * kb[d];
    }
    for (int j4 = 0; j4 < 32; ++j4) {
      f32x4 tv4 = *(const f32x4*)&T12[which][tr][j4 * 4];
#pragma unroll
      for (int j = 0; j < 4; ++j) {
        f32x4 w4 = *(const f32x4*)&Big[L + 32 * j][j4 * 4];
        g[j] += tv4[0]*w4[0] + tv4[1]*w4[1] + tv4[2]*w4[2] + tv4[3]*w4[3];
      }
    }
    float m = fmaxf(fmaxf(g[0], g[1]), fmaxf(g[2], g[3]));
#pragma unroll
    for (int off = 1; off < 32; off <<= 1) m = fmaxf(m, __shfl_xor(m, off));
    float s = 0.f;
#pragma unroll
    for (int j = 0; j < 4; ++j) { g[j] = expf(g[j] - m); s += g[j]; }
#pragma unroll
    for (int off = 1; off < 32; off <<= 1) s += __shfl_xor(s, off);
    const float inv = 1.f / s;
    float* A = (which ? Ats : Ast) + (size_t)b * CC * CC + (size_t)c * CC;
#pragma unroll
    for (int j = 0; j < 4; ++j) A[L + 32 * j] = g[j] * inv;
  }
}

// ---------------------------------------------------------------------------
// K2cd fused: L = Ast*Ats^T, softmax -> Att, P' = Att*Wv + I (bf16), c0.
// grid (16 c-groups of 8 rows, 8 b).
// ---------------------------------------------------------------------------
__global__ __launch_bounds__(256) void k2cd(const float* __restrict__ Ast,
    const float* __restrict__ Ats, const float* __restrict__ vw,
    const float* __restrict__ vb, unsigned short* __restrict__ Pbf,
    float* __restrict__ c0v) {
  const int b = blockIdx.y;
  const int c0 = blockIdx.x * 8;
  __shared__ float Big[128][132];      // Ats, later Wv[d][i]
  __shared__ float Tl[8][128];
  __shared__ float Al[8][128];
  const int t = threadIdx.x;
  const float* Bb = Ats + (size_t)b * CC * CC;
  const float* Tb = Ast + (size_t)b * CC * CC;
#pragma unroll
  for (int p = 0; p < 16; ++p) {
    int f = p * 256 + t;
    int row = f >> 5, c4 = (f & 31) * 4;
    *(f32x4*)&Big[row][c4] = *(const f32x4*)(Bb + row * CC + c4);
  }
  { int row = t >> 5, c4 = (t & 31) * 4;
    *(f32x4*)&Tl[row][c4] = *(const f32x4*)(Tb + (c0 + row) * CC + c4); }
  __syncthreads();
  const int tr = t >> 5;
  const int L = t & 31;
  {
    float g[4] = {0.f, 0.f, 0.f, 0.f};
    for (int e4 = 0; e4 < 32; ++e4) {
      f32x4 tv4 = *(const f32x4*)&Tl[tr][e4 * 4];
#pragma unroll
      for (int j = 0; j < 4; ++j) {
        f32x4 a4 = *(const f32x4*)&Big[L + 32 * j][e4 * 4];
        g[j] += tv4[0]*a4[0] + tv4[1]*a4[1] + tv4[2]*a4[2] + tv4[3]*a4[3];
      }
    }
    float m = fmaxf(fmaxf(g[0], g[1]), fmaxf(g[2], g[3]));
#pragma unroll
    for (int off = 1; off < 32; off <<= 1) m = fmaxf(m, __shfl_xor(m, off));
    float s = 0.f;
#pragma unroll
    for (int j = 0; j < 4; ++j) { g[j] = expf(g[j] - m); s += g[j]; }
#pragma unroll
    for (int off = 1; off < 32; off <<= 1) s += __shfl_xor(s, off);
    const float inv = 1.f / s;
#pragma unroll
    for (int j = 0; j < 4; ++j) Al[tr][L + 32 * j] = g[j] * inv;
  }
  __syncthreads();
  // overwrite Big with Wv[d][i]
#pragma unroll
  for (int p = 0; p < 16; ++p) {
    int f = p * 256 + t;
    int row = f >> 5, c4 = (f & 31) * 4;
    *(f32x4*)&Big[row][c4] = *(const f32x4*)(vw + row * CC + c4);
  }
  __syncthreads();
  float p4[4] = {0.f, 0.f, 0.f, 0.f};
  for (int d = 0; d < CC; ++d) {
    float av = Al[tr][d];
#pragma unroll
    for (int j = 0; j < 4; ++j) p4[j] += av * Big[d][L + 32 * j];
  }
  float csum = 0.f;
#pragma unroll
  for (int j = 0; j < 4; ++j) csum += Al[tr][L + 32 * j] * vb[L + 32 * j];
#pragma unroll
  for (int off = 1; off < 32; off <<= 1) csum += __shfl_xor(csum, off);
  const int c = c0 + tr;
  if ((c & 31) == L) p4[c >> 5] += 1.0f;      // P' = P + I (residual folded in)
  unsigned short* Pp = Pbf + (size_t)b * CC * CC + (size_t)c * CC;
#pragma unroll
  for (int j = 0; j < 4; ++j) Pp[L + 32 * j] = (unsigned short)bf16rne(p4[j]);
  if (L == 0) c0v[b * CC + c] = csum;
}

// ---------------------------------------------------------------------------
// K3 (MFMA): out[c][n] = sum_e P'[c][e]*x[e][n] + c0[c]  (identity in P').
// X tile -> LDS transposed bf16 (swizzled); P' frags straight from L1/L2.
// grid (256 n-tiles, 16 images), 4 waves, 4 blocks/CU.
// ---------------------------------------------------------------------------
__global__ __launch_bounds__(256, 4) void k3_mfma(const float* __restrict__ x,
    const unsigned short* __restrict__ Pbf, const float* __restrict__ c0v,
    float* __restrict__ out) {
  const int im = blockIdx.y;
  const int pb = im & 7;
  const int nb = blockIdx.x * 64;
  const float* X = x + (size_t)im * NFULL;
  float* O = out + (size_t)im * NFULL;
  __shared__ unsigned short XT[64 * 128];    // swizzled: byte ^ (((n>>2)&15)<<4)
  __shared__ float c0l[128];
  const int t = threadIdx.x;
  if (t < 128) c0l[t] = c0v[pb * CC + t];
#pragma unroll
  for (int p = 0; p < 4; ++p) {
    int d0 = 2 * (t >> 4) + 32 * p;
    int n4 = (t & 15) * 4;
    f32x4 x0 = *(const f32x4*)(X + (size_t)d0 * NSP + nb + n4);
    f32x4 x1 = *(const f32x4*)(X + (size_t)(d0 + 1) * NSP + nb + n4);
#pragma unroll
    for (int i = 0; i < 4; ++i) {
      int n = n4 + i;
      unsigned pk = bf16rne(x0[i]) | (bf16rne(x1[i]) << 16);
      int off = (n * 256 + d0 * 2) ^ (((n >> 2) & 15) << 4);
      *(unsigned*)((char*)XT + off) = pk;
    }
  }
  __syncthreads();

  const int w = t >> 6, l = t & 63;
  const int ln = l & 15, lg = l >> 4;
  const int n = nb + w * 16 + ln;
  s16x8 bf[4];
  {
    int row = w * 16 + ln;
    int sw = ((row >> 2) & 15) << 4;
#pragma unroll
    for (int kk = 0; kk < 4; ++kk)
      bf[kk] = *(const s16x8*)((char*)XT + ((row * 256 + kk * 64 + lg * 16) ^ sw));
  }
  const unsigned short* Pg = Pbf + (size_t)pb * (CC * CC) + (size_t)ln * CC + lg * 8;
  f32x4 acc[8];
#pragma unroll
  for (int a = 0; a < 8; ++a) acc[a] = (f32x4){0.f, 0.f, 0.f, 0.f};
#pragma unroll
  for (int a = 0; a < 8; ++a) {
#pragma unroll
    for (int kk = 0; kk < 4; ++kk) {
      s16x8 af = *(const s16x8*)(Pg + a * 16 * CC + kk * 32);
      acc[a] = __builtin_amdgcn_mfma_f32_16x16x32_bf16(af, bf[kk], acc[a], 0, 0, 0);
    }
  }
#pragma unroll
  for (int a = 0; a < 8; ++a) {
#pragma unroll
    for (int r = 0; r < 4; ++r) {
      int c = a * 16 + lg * 4 + r;
      O[(size_t)c * NSP + n] = acc[a][r] + c0l[c];
    }
  }
}

// ---------------------------------------------------------------------------
extern "C" void kernel_launch(void* const* d_in, const int* in_sizes, int n_in,
                              void* d_out, int out_size, void* d_ws, size_t ws_size,
                              hipStream_t stream) {
  (void)in_sizes; (void)n_in; (void)out_size;
  const float* x  = (const float*)d_in[0];
  const float* qw = (const float*)d_in[1];
  const float* qb = (const float*)d_in[2];
  const float* kw = (const float*)d_in[3];
  const float* kb = (const float*)d_in[4];
  const float* vw = (const float*)d_in[5];
  const float* vb = (const float*)d_in[6];
  float* out = (float*)d_out;
  float* ws = (float*)d_ws;
  float* M   = ws;                       // 8*128*128  (M, rs, rt contiguous)
  float* rs  = M + 131072;               // 8*128
  float* rt  = rs + 1024;
  float* AST = rt + 1024;                // 8*128*128
  float* ATS = AST + 131072;
  unsigned short* Pbf = (unsigned short*)(ATS + 131072);  // 8*128*128 bf16
  float* c0v = ATS + 131072 + 65536;
  float* Mpart = c0v + 1024;
  const size_t base_floats = (size_t)(Mpart - ws);

  int NB, mode;
  if (ws_size >= (base_floats + (size_t)64 * (131072 + 2048)) * 4) { NB = 64; mode = 0; }
  else if (ws_size >= (base_floats + (size_t)32 * (131072 + 2048)) * 4) { NB = 32; mode = 0; }
  else { NB = 32; mode = 1; }
  const int nsteps = (16384 / NB) / 32;
  float* rtpart = Mpart + (size_t)NB * 131072;   // NB*8*128
  float* rspart = rtpart + (size_t)NB * 1024;    // NB*8*128

  if (mode == 1) zerok<<<(133120 + 255) / 256, 256, 0, stream>>>(M, 133120);
  k1_mfma<<<dim3(NB, 8), 256, 0, stream>>>(x, mode ? M : Mpart, rs, rt,
                                           rspart, rtpart, nsteps, mode);
  if (mode == 0)
    k1_reduce<<<130, 256, 0, stream>>>(Mpart, rspart, rtpart, M, rs, rt, NB);
  k2ab<<<dim3(16, 8), 256, 0, stream>>>(M, qw, kw, qb, kb, rs, rt, AST, ATS);
  k2cd<<<dim3(16, 8), 256, 0, stream>>>(AST, ATS, vw, vb, Pbf, c0v);
  k3_mfma<<<dim3(256, 16), 256, 0, stream>>>(x, Pbf, c0v, out);
}

// Round 6
// 157.228 us; speedup vs baseline: 3.4553x; 1.2771x over previous
//
#include <hip/hip_runtime.h>
#include <hip/hip_bf16.h>

#define CC 128
#define NSP 16384              // 128*128 spatial
#define NFULL (CC * NSP)

typedef float f32x4 __attribute__((ext_vector_type(4)));
typedef short s16x8 __attribute__((ext_vector_type(8)));
typedef unsigned int u32x4 __attribute__((ext_vector_type(4)));

__device__ __forceinline__ unsigned bf16rne(float f) {
  unsigned u = __float_as_uint(f);
  return ((u + 0x7FFFu + ((u >> 16) & 1u)) >> 16) & 0xFFFFu;
}

// fp32[8] -> bf16 hi frag + bf16 lo frag (for K1 hi/lo split)
__device__ __forceinline__ void cvt8(const float* v, s16x8& hi, s16x8& lo) {
  unsigned ph[4], pl[4];
#pragma unroll
  for (int k = 0; k < 4; ++k) {
    unsigned u0 = __float_as_uint(v[2 * k]);
    unsigned u1 = __float_as_uint(v[2 * k + 1]);
    ph[k] = (u1 & 0xFFFF0000u) | (u0 >> 16);
    float h0 = __uint_as_float(u0 & 0xFFFF0000u);
    float h1 = __uint_as_float(u1 & 0xFFFF0000u);
    unsigned l0 = __float_as_uint(v[2 * k] - h0);
    unsigned l1 = __float_as_uint(v[2 * k + 1] - h1);
    pl[k] = (l1 & 0xFFFF0000u) | (l0 >> 16);
  }
  u32x4 H = {ph[0], ph[1], ph[2], ph[3]};
  u32x4 L = {pl[0], pl[1], pl[2], pl[3]};
  hi = __builtin_bit_cast(s16x8, H);
  lo = __builtin_bit_cast(s16x8, L);
}

// zero M/rs/rt (mode-1 fallback only)
__global__ __launch_bounds__(256) void zerok(float* __restrict__ p, int n) {
  int i = blockIdx.x * 256 + threadIdx.x;
  if (i < n) p[i] = 0.f;
}

// ---------------------------------------------------------------------------
// K1 (MFMA): per batch b, chunk: partial Xt*Xs^T over n-chunk (hi/lo split).
// ---------------------------------------------------------------------------
__global__ __launch_bounds__(256, 2) void k1_mfma(const float* __restrict__ x,
    float* __restrict__ Mdst, float* __restrict__ rs, float* __restrict__ rt,
    float* __restrict__ rspart, float* __restrict__ rtpart,
    int nsteps, int mode) {
  const int b = blockIdx.y;
  const int chunk = blockIdx.x;
  const int n0 = chunk * (nsteps * 32);
  const int t = threadIdx.x;
  const int w = t >> 6, l = t & 63;
  const int wr = w >> 1, wc = w & 1;
  const int lr = l & 15;
  const int lk = (l >> 4) << 3;
  const float* Xs = x + (size_t)b * NFULL;
  const float* Xt = x + (size_t)(b + 8) * NFULL;
  const float* Ab = Xt + (size_t)(wr * 64 + lr) * NSP + n0 + lk;
  const float* Bb = Xs + (size_t)(wc * 64 + lr) * NSP + n0 + lk;

  f32x4 acc[4][4];
#pragma unroll
  for (int a = 0; a < 4; ++a)
#pragma unroll
    for (int bb = 0; bb < 4; ++bb) acc[a][bb] = (f32x4){0.f, 0.f, 0.f, 0.f};
  float rtp[4] = {0.f, 0.f, 0.f, 0.f};
  float rsp[4] = {0.f, 0.f, 0.f, 0.f};

  for (int s = 0; s < nsteps; ++s) {
    const float* ap = Ab + s * 32;
    const float* bp = Bb + s * 32;
    s16x8 ahi[4], alo[4], bhi[4], blo[4];
    {
      float ar[4][8];
#pragma unroll
      for (int a = 0; a < 4; ++a) {
        *(f32x4*)&ar[a][0] = *(const f32x4*)(ap + (size_t)a * 16 * NSP);
        *(f32x4*)&ar[a][4] = *(const f32x4*)(ap + (size_t)a * 16 * NSP + 4);
      }
      if (wc == 0) {
#pragma unroll
        for (int a = 0; a < 4; ++a) {
          float s0 = (ar[a][0] + ar[a][1]) + (ar[a][2] + ar[a][3]);
          float s1 = (ar[a][4] + ar[a][5]) + (ar[a][6] + ar[a][7]);
          rtp[a] += s0 + s1;
        }
      }
#pragma unroll
      for (int a = 0; a < 4; ++a) cvt8(ar[a], ahi[a], alo[a]);
    }
    {
      float br[4][8];
#pragma unroll
      for (int bb = 0; bb < 4; ++bb) {
        *(f32x4*)&br[bb][0] = *(const f32x4*)(bp + (size_t)bb * 16 * NSP);
        *(f32x4*)&br[bb][4] = *(const f32x4*)(bp + (size_t)bb * 16 * NSP + 4);
      }
      if (wr == 0) {
#pragma unroll
        for (int bb = 0; bb < 4; ++bb) {
          float s0 = (br[bb][0] + br[bb][1]) + (br[bb][2] + br[bb][3]);
          float s1 = (br[bb][4] + br[bb][5]) + (br[bb][6] + br[bb][7]);
          rsp[bb] += s0 + s1;
        }
      }
#pragma unroll
      for (int bb = 0; bb < 4; ++bb) cvt8(br[bb], bhi[bb], blo[bb]);
    }
#pragma unroll
    for (int a = 0; a < 4; ++a)
#pragma unroll
      for (int bb = 0; bb < 4; ++bb) {
        acc[a][bb] = __builtin_amdgcn_mfma_f32_16x16x32_bf16(ahi[a], bhi[bb], acc[a][bb], 0, 0, 0);
        acc[a][bb] = __builtin_amdgcn_mfma_f32_16x16x32_bf16(ahi[a], blo[bb], acc[a][bb], 0, 0, 0);
        acc[a][bb] = __builtin_amdgcn_mfma_f32_16x16x32_bf16(alo[a], bhi[bb], acc[a][bb], 0, 0, 0);
      }
  }

  if (wc == 0) {
#pragma unroll
    for (int a = 0; a < 4; ++a) {
      float v = rtp[a];
      v += __shfl_xor(v, 16);
      v += __shfl_xor(v, 32);
      if (l < 16) {
        int i = wr * 64 + a * 16 + l;
        if (mode == 0) rtpart[((size_t)chunk * 8 + b) * CC + i] = v;
        else atomicAdd(&rt[b * CC + i], v);
      }
    }
  }
  if (wr == 0) {
#pragma unroll
    for (int bb = 0; bb < 4; ++bb) {
      float v = rsp[bb];
      v += __shfl_xor(v, 16);
      v += __shfl_xor(v, 32);
      if (l < 16) {
        int j = wc * 64 + bb * 16 + l;
        if (mode == 0) rspart[((size_t)chunk * 8 + b) * CC + j] = v;
        else atomicAdd(&rs[b * CC + j], v);
      }
    }
  }

  const int rquad = (l >> 4) << 2;
  if (mode == 0) {
    float* Mp = Mdst + ((size_t)chunk * 8 + b) * (CC * CC);
#pragma unroll
    for (int a = 0; a < 4; ++a)
#pragma unroll
      for (int bb = 0; bb < 4; ++bb)
#pragma unroll
        for (int r = 0; r < 4; ++r) {
          int i = wr * 64 + a * 16 + rquad + r;
          int j = wc * 64 + bb * 16 + lr;
          Mp[i * CC + j] = acc[a][bb][r];
        }
  } else {
    float* Mp = Mdst + (size_t)b * (CC * CC);
#pragma unroll
    for (int a = 0; a < 4; ++a)
#pragma unroll
      for (int bb = 0; bb < 4; ++bb)
#pragma unroll
        for (int r = 0; r < 4; ++r) {
          int i = wr * 64 + a * 16 + rquad + r;
          int j = wc * 64 + bb * 16 + lr;
          atomicAdd(&Mp[i * CC + j], acc[a][bb][r]);
        }
  }
}

// Sum partials, vectorized. Blocks [0,128): M. Block 128: rt. Block 129: rs.
__global__ __launch_bounds__(256) void k1_reduce(const float* __restrict__ Mpart,
    const float* __restrict__ rspart, const float* __restrict__ rtpart,
    float* __restrict__ M, float* __restrict__ rs, float* __restrict__ rt,
    int NB) {
  const int t = threadIdx.x;
  if (blockIdx.x < 128) {
    const int i4 = blockIdx.x * 256 + t;     // < 32768
    const int b = i4 >> 12;
    const int e = (i4 & 4095) * 4;
    f32x4 s = (f32x4){0.f, 0.f, 0.f, 0.f};
    for (int c = 0; c < NB; ++c) {
      f32x4 v = *(const f32x4*)(Mpart + ((size_t)c * 8 + b) * (CC * CC) + e);
      s += v;
    }
    *(f32x4*)(M + (size_t)b * CC * CC + e) = s;
  } else if (blockIdx.x == 128) {
    const int e = t * 4;                      // < 1024
    f32x4 s = (f32x4){0.f, 0.f, 0.f, 0.f};
    for (int c = 0; c < NB; ++c) s += *(const f32x4*)(rtpart + (size_t)c * 1024 + e);
    *(f32x4*)(rt + e) = s;
  } else {
    const int e = t * 4;
    f32x4 s = (f32x4){0.f, 0.f, 0.f, 0.f};
    for (int c = 0; c < NB; ++c) s += *(const f32x4*)(rspart + (size_t)c * 1024 + e);
    *(f32x4*)(rs + e) = s;
  }
}

// ---------------------------------------------------------------------------
// K2ab fused: T1=Wq*M, T2=Wq*M^T, us/ut, G + softmax (st & ts).
// grid (16 c-groups of 8 rows, 8 b). Cols strided: lane L owns {L+32j}.
// ---------------------------------------------------------------------------
__global__ __launch_bounds__(256) void k2ab(const float* __restrict__ M,
    const float* __restrict__ qw, const float* __restrict__ kw,
    const float* __restrict__ qb, const float* __restrict__ kb,
    const float* __restrict__ rs, const float* __restrict__ rt,
    float* __restrict__ Ast, float* __restrict__ Ats) {
  const int b = blockIdx.y;
  const int c0 = blockIdx.x * 8;
  __shared__ float Big[128][132];      // M, later Wk (132: 16B-aligned rows)
  __shared__ float Wq[8][128];
  __shared__ float T12[2][8][128];
  __shared__ float uvv[2][8];
  __shared__ float wv2[2][128];
  const int t = threadIdx.x;
  const float* Mb = M + (size_t)b * CC * CC;
#pragma unroll
  for (int p = 0; p < 16; ++p) {
    int f = p * 256 + t;
    int row = f >> 5, c4 = (f & 31) * 4;
    *(f32x4*)&Big[row][c4] = *(const f32x4*)(Mb + row * CC + c4);
  }
  { int row = t >> 5, c4 = (t & 31) * 4;
    *(f32x4*)&Wq[row][c4] = *(const f32x4*)(qw + (c0 + row) * CC + c4); }
  __syncthreads();
  if (t < 16) {
    int c = t & 7;
    const float* r = ((t < 8) ? rs : rt) + b * CC;
    float s = 0.f;
    for (int i = 0; i < CC; ++i) s += Wq[c][i] * r[i];
    uvv[(t < 8) ? 1 : 0][c] = s;       // us->[1], ut->[0]
  }
  const int tr = t >> 5;               // row 0..7
  const int L = t & 31;                // col lane
  {
    float a1[4] = {0.f, 0.f, 0.f, 0.f}, a2[4] = {0.f, 0.f, 0.f, 0.f};
    for (int i = 0; i < CC; ++i) {
      float wq = Wq[tr][i];
#pragma unroll
      for (int j = 0; j < 4; ++j) a1[j] += wq * Big[i][L + 32 * j];
    }
    for (int i4 = 0; i4 < 32; ++i4) {
      f32x4 wq4 = *(const f32x4*)&Wq[tr][i4 * 4];
#pragma unroll
      for (int j = 0; j < 4; ++j) {
        f32x4 m4 = *(const f32x4*)&Big[L + 32 * j][i4 * 4];
        a2[j] += wq4[0]*m4[0] + wq4[1]*m4[1] + wq4[2]*m4[2] + wq4[3]*m4[3];
      }
    }
#pragma unroll
    for (int j = 0; j < 4; ++j) {
      T12[0][tr][L + 32 * j] = a1[j];
      T12[1][tr][L + 32 * j] = a2[j];
    }
  }
  __syncthreads();
  // overwrite Big with Wk
#pragma unroll
  for (int p = 0; p < 16; ++p) {
    int f = p * 256 + t;
    int row = f >> 5, c4 = (f & 31) * 4;
    *(f32x4*)&Big[row][c4] = *(const f32x4*)(kw + row * CC + c4);
  }
  __syncthreads();
  {
    int d = t & 127, wh = t >> 7;      // 0: rs, 1: rt
    const float* r = (wh ? rt : rs) + b * CC;
    float s = 0.f;
    for (int i4 = 0; i4 < 32; ++i4) {
      f32x4 w4 = *(const f32x4*)&Big[d][i4 * 4];
      s += w4[0]*r[i4*4] + w4[1]*r[i4*4+1] + w4[2]*r[i4*4+2] + w4[3]*r[i4*4+3];
    }
    wv2[wh][d] = s;
  }
  __syncthreads();
  const int c = c0 + tr;
  const float bqc = qb[c];
#pragma unroll 1
  for (int which = 0; which < 2; ++which) {
    float g[4];
#pragma unroll
    for (int j = 0; j < 4; ++j) {
      int d = L + 32 * j;
      g[j] = uvv[which][tr] * kb[d] + bqc * wv2[which][d] + 16384.f * bqc * kb[d];
    }
    for (int j4 = 0; j4 < 32; ++j4) {
      f32x4 tv4 = *(const f32x4*)&T12[which][tr][j4 * 4];
#pragma unroll
      for (int j = 0; j < 4; ++j) {
        f32x4 w4 = *(const f32x4*)&Big[L + 32 * j][j4 * 4];
        g[j] += tv4[0]*w4[0] + tv4[1]*w4[1] + tv4[2]*w4[2] + tv4[3]*w4[3];
      }
    }
    float m = fmaxf(fmaxf(g[0], g[1]), fmaxf(g[2], g[3]));
#pragma unroll
    for (int off = 1; off < 32; off <<= 1) m = fmaxf(m, __shfl_xor(m, off));
    float s = 0.f;
#pragma unroll
    for (int j = 0; j < 4; ++j) { g[j] = expf(g[j] - m); s += g[j]; }
#pragma unroll
    for (int off = 1; off < 32; off <<= 1) s += __shfl_xor(s, off);
    const float inv = 1.f / s;
    float* A = (which ? Ats : Ast) + (size_t)b * CC * CC + (size_t)c * CC;
#pragma unroll
    for (int j = 0; j < 4; ++j) A[L + 32 * j] = g[j] * inv;
  }
}

// ---------------------------------------------------------------------------
// K2cd fused: L = Ast*Ats^T, softmax -> Att, P' = Att*Wv + I (bf16), c0.
// grid (16 c-groups of 8 rows, 8 b).
// ---------------------------------------------------------------------------
__global__ __launch_bounds__(256) void k2cd(const float* __restrict__ Ast,
    const float* __restrict__ Ats, const float* __restrict__ vw,
    const float* __restrict__ vb, unsigned short* __restrict__ Pbf,
    float* __restrict__ c0v) {
  const int b = blockIdx.y;
  const int c0 = blockIdx.x * 8;
  __shared__ float Big[128][132];      // Ats, later Wv[d][i]
  __shared__ float Tl[8][128];
  __shared__ float Al[8][128];
  const int t = threadIdx.x;
  const float* Bb = Ats + (size_t)b * CC * CC;
  const float* Tb = Ast + (size_t)b * CC * CC;
#pragma unroll
  for (int p = 0; p < 16; ++p) {
    int f = p * 256 + t;
    int row = f >> 5, c4 = (f & 31) * 4;
    *(f32x4*)&Big[row][c4] = *(const f32x4*)(Bb + row * CC + c4);
  }
  { int row = t >> 5, c4 = (t & 31) * 4;
    *(f32x4*)&Tl[row][c4] = *(const f32x4*)(Tb + (c0 + row) * CC + c4); }
  __syncthreads();
  const int tr = t >> 5;
  const int L = t & 31;
  {
    float g[4] = {0.f, 0.f, 0.f, 0.f};
    for (int e4 = 0; e4 < 32; ++e4) {
      f32x4 tv4 = *(const f32x4*)&Tl[tr][e4 * 4];
#pragma unroll
      for (int j = 0; j < 4; ++j) {
        f32x4 a4 = *(const f32x4*)&Big[L + 32 * j][e4 * 4];
        g[j] += tv4[0]*a4[0] + tv4[1]*a4[1] + tv4[2]*a4[2] + tv4[3]*a4[3];
      }
    }
    float m = fmaxf(fmaxf(g[0], g[1]), fmaxf(g[2], g[3]));
#pragma unroll
    for (int off = 1; off < 32; off <<= 1) m = fmaxf(m, __shfl_xor(m, off));
    float s = 0.f;
#pragma unroll
    for (int j = 0; j < 4; ++j) { g[j] = expf(g[j] - m); s += g[j]; }
#pragma unroll
    for (int off = 1; off < 32; off <<= 1) s += __shfl_xor(s, off);
    const float inv = 1.f / s;
#pragma unroll
    for (int j = 0; j < 4; ++j) Al[tr][L + 32 * j] = g[j] * inv;
  }
  __syncthreads();
  // overwrite Big with Wv[d][i]
#pragma unroll
  for (int p = 0; p < 16; ++p) {
    int f = p * 256 + t;
    int row = f >> 5, c4 = (f & 31) * 4;
    *(f32x4*)&Big[row][c4] = *(const f32x4*)(vw + row * CC + c4);
  }
  __syncthreads();
  float p4[4] = {0.f, 0.f, 0.f, 0.f};
  for (int d = 0; d < CC; ++d) {
    float av = Al[tr][d];
#pragma unroll
    for (int j = 0; j < 4; ++j) p4[j] += av * Big[d][L + 32 * j];
  }
  float csum = 0.f;
#pragma unroll
  for (int j = 0; j < 4; ++j) csum += Al[tr][L + 32 * j] * vb[L + 32 * j];
#pragma unroll
  for (int off = 1; off < 32; off <<= 1) csum += __shfl_xor(csum, off);
  const int c = c0 + tr;
  if ((c & 31) == L) p4[c >> 5] += 1.0f;      // P' = P + I (residual folded in)
  unsigned short* Pp = Pbf + (size_t)b * CC * CC + (size_t)c * CC;
#pragma unroll
  for (int j = 0; j < 4; ++j) Pp[L + 32 * j] = (unsigned short)bf16rne(p4[j]);
  if (L == 0) c0v[b * CC + c] = csum;
}

// ---------------------------------------------------------------------------
// K3 (MFMA): out[c][n] = sum_e P'[c][e]*x[e][n] + c0[c]  (identity in P').
// 256-n tile per block staged ONCE to LDS (transposed bf16, swizzled);
// P' fragments hoisted to registers per c-half and reused across 4 subtiles.
// Output via nontemporal stores (never re-read; keep x resident in L3).
// grid (64 n-tiles, 16 images), 4 waves, 2 blocks/CU (66KB LDS).
// ---------------------------------------------------------------------------
__global__ __launch_bounds__(256, 2) void k3_mfma(const float* __restrict__ x,
    const unsigned short* __restrict__ Pbf, const float* __restrict__ c0v,
    float* __restrict__ out) {
  const int im = blockIdx.y;
  const int pb = im & 7;
  const int n0 = blockIdx.x * 256;
  const float* X = x + (size_t)im * NFULL;
  float* O = out + (size_t)im * NFULL;
  __shared__ unsigned short XT[256 * 128];   // swizzled: byte ^ (((n>>2)&15)<<4)
  __shared__ float c0l[128];
  const int t = threadIdx.x;
  if (t < 128) c0l[t] = c0v[pb * CC + t];
#pragma unroll
  for (int p = 0; p < 16; ++p) {
    int d0 = 2 * (t >> 4) + 32 * (p & 3);
    int n4 = (t & 15) * 4 + 64 * (p >> 2);
    f32x4 x0 = *(const f32x4*)(X + (size_t)d0 * NSP + n0 + n4);
    f32x4 x1 = *(const f32x4*)(X + (size_t)(d0 + 1) * NSP + n0 + n4);
#pragma unroll
    for (int i = 0; i < 4; ++i) {
      int n = n4 + i;
      __hip_bfloat162 h2 = __float22bfloat162_rn(make_float2(x0[i], x1[i]));
      unsigned pk = *reinterpret_cast<unsigned*>(&h2);
      int off = (n * 256 + d0 * 2) ^ (((n >> 2) & 15) << 4);
      *(unsigned*)((char*)XT + off) = pk;
    }
  }
  __syncthreads();

  const int w = t >> 6, l = t & 63;
  const int ln = l & 15, lg = l >> 4;
#pragma unroll
  for (int h = 0; h < 2; ++h) {
    // hoist this c-half's P' fragments into registers, reuse over 4 subtiles
    const unsigned short* Pg = Pbf + (size_t)pb * (CC * CC)
                             + (size_t)(h * 64 + ln) * CC + lg * 8;
    s16x8 Af[4][4];
#pragma unroll
    for (int a = 0; a < 4; ++a)
#pragma unroll
      for (int kk = 0; kk < 4; ++kk)
        Af[a][kk] = *(const s16x8*)(Pg + a * 16 * CC + kk * 32);
#pragma unroll
    for (int sub = 0; sub < 4; ++sub) {
      int row = sub * 64 + w * 16 + ln;
      int sw = ((row >> 2) & 15) << 4;
      s16x8 bf[4];
#pragma unroll
      for (int kk = 0; kk < 4; ++kk)
        bf[kk] = *(const s16x8*)((char*)XT + ((row * 256 + kk * 64 + lg * 16) ^ sw));
      f32x4 acc[4];
#pragma unroll
      for (int a = 0; a < 4; ++a) acc[a] = (f32x4){0.f, 0.f, 0.f, 0.f};
#pragma unroll
      for (int kk = 0; kk < 4; ++kk)
#pragma unroll
        for (int a = 0; a < 4; ++a)
          acc[a] = __builtin_amdgcn_mfma_f32_16x16x32_bf16(Af[a][kk], bf[kk], acc[a], 0, 0, 0);
      int n = n0 + sub * 64 + w * 16 + ln;
#pragma unroll
      for (int a = 0; a < 4; ++a)
#pragma unroll
        for (int r = 0; r < 4; ++r) {
          int c = h * 64 + a * 16 + lg * 4 + r;
          __builtin_nontemporal_store(acc[a][r] + c0l[c], O + (size_t)c * NSP + n);
        }
    }
  }
}

// ---------------------------------------------------------------------------
extern "C" void kernel_launch(void* const* d_in, const int* in_sizes, int n_in,
                              void* d_out, int out_size, void* d_ws, size_t ws_size,
                              hipStream_t stream) {
  (void)in_sizes; (void)n_in; (void)out_size;
  const float* x  = (const float*)d_in[0];
  const float* qw = (const float*)d_in[1];
  const float* qb = (const float*)d_in[2];
  const float* kw = (const float*)d_in[3];
  const float* kb = (const float*)d_in[4];
  const float* vw = (const float*)d_in[5];
  const float* vb = (const float*)d_in[6];
  float* out = (float*)d_out;
  float* ws = (float*)d_ws;
  float* M   = ws;                       // 8*128*128  (M, rs, rt contiguous)
  float* rs  = M + 131072;               // 8*128
  float* rt  = rs + 1024;
  float* AST = rt + 1024;                // 8*128*128
  float* ATS = AST + 131072;
  unsigned short* Pbf = (unsigned short*)(ATS + 131072);  // 8*128*128 bf16
  float* c0v = ATS + 131072 + 65536;
  float* Mpart = c0v + 1024;
  const size_t base_floats = (size_t)(Mpart - ws);

  int NB, mode;
  if (ws_size >= (base_floats + (size_t)64 * (131072 + 2048)) * 4) { NB = 64; mode = 0; }
  else if (ws_size >= (base_floats + (size_t)32 * (131072 + 2048)) * 4) { NB = 32; mode = 0; }
  else { NB = 32; mode = 1; }
  const int nsteps = (16384 / NB) / 32;
  float* rtpart = Mpart + (size_t)NB * 131072;   // NB*8*128
  float* rspart = rtpart + (size_t)NB * 1024;    // NB*8*128

  if (mode == 1) zerok<<<(133120 + 255) / 256, 256, 0, stream>>>(M, 133120);
  k1_mfma<<<dim3(NB, 8), 256, 0, stream>>>(x, mode ? M : Mpart, rs, rt,
                                           rspart, rtpart, nsteps, mode);
  if (mode == 0)
    k1_reduce<<<130, 256, 0, stream>>>(Mpart, rspart, rtpart, M, rs, rt, NB);
  k2ab<<<dim3(16, 8), 256, 0, stream>>>(M, qw, kw, qb, kb, rs, rt, AST, ATS);
  k2cd<<<dim3(16, 8), 256, 0, stream>>>(AST, ATS, vw, vb, Pbf, c0v);
  k3_mfma<<<dim3(64, 16), 256, 0, stream>>>(x, Pbf, c0v, out);
}

// Round 8
// 145.601 us; speedup vs baseline: 3.7312x; 1.0799x over previous
//
#include <hip/hip_runtime.h>
#include <hip/hip_bf16.h>

#define CC 128
#define NSP 16384              // 128*128 spatial
#define NFULL (CC * NSP)

typedef float f32x4 __attribute__((ext_vector_type(4)));
typedef short s16x8 __attribute__((ext_vector_type(8)));
typedef unsigned int u32x4 __attribute__((ext_vector_type(4)));

__device__ __forceinline__ unsigned bf16rne(float f) {
  unsigned u = __float_as_uint(f);
  return ((u + 0x7FFFu + ((u >> 16) & 1u)) >> 16) & 0xFFFFu;
}

// RNE hi/lo split of a float pair -> packed {hi, lo} u32 (bf16x2 each)
__device__ __forceinline__ uint2 packpair(float x0, float x1) {
  __hip_bfloat162 h2 = __float22bfloat162_rn(make_float2(x0, x1));
  unsigned hu = *reinterpret_cast<unsigned*>(&h2);   // lo16=bf16(x0), hi16=bf16(x1)
  float hf0 = __uint_as_float(hu << 16);
  float hf1 = __uint_as_float(hu & 0xFFFF0000u);
  __hip_bfloat162 l2 = __float22bfloat162_rn(make_float2(x0 - hf0, x1 - hf1));
  unsigned lu = *reinterpret_cast<unsigned*>(&l2);
  return make_uint2(hu, lu);
}

// zero M/rs/rt (mode-1 fallback only)
__global__ __launch_bounds__(256) void zerok(float* __restrict__ p, int n) {
  int i = blockIdx.x * 256 + threadIdx.x;
  if (i < n) p[i] = 0.f;
}

// ---------------------------------------------------------------------------
// K1 (MFMA, LDS-staged): per (chunk,b): partial Xt*Xs^T over 64-n stages.
// Stage: 128 rows x 64 n of Xt and Xs converted ONCE to hi/lo bf16 in
// XOR-swizzled LDS; 4 waves (2x2) each compute a 64x64 tile via 96 MFMA
// (hi*hi + hi*lo + lo*hi) per stage. Row sums fold into staging.
// ---------------------------------------------------------------------------
__global__ __launch_bounds__(256, 2) void k1_mfma(const float* __restrict__ x,
    float* __restrict__ Mdst, float* __restrict__ rs, float* __restrict__ rt,
    float* __restrict__ rspart, float* __restrict__ rtpart,
    int nst, int mode) {
  const int b = blockIdx.y;
  const int chunk = blockIdx.x;
  const int n0 = chunk * (nst * 64);
  const int t = threadIdx.x;
  const int w = t >> 6, l = t & 63;
  const int wr = w >> 1, wc = w & 1;
  const int lr = l & 15, lg = l >> 4;
  const int r0 = t >> 2;               // staging row 0..63 (and +64)
  const int q = t & 3;                 // staging n-quarter (16 floats)
  __shared__ unsigned short Ahi[128 * 64];   // 16KB each, swz: byte^((row&7)<<4)
  __shared__ unsigned short Alo[128 * 64];
  __shared__ unsigned short Bhi[128 * 64];
  __shared__ unsigned short Blo[128 * 64];
  const float* Xs = x + (size_t)b * NFULL;
  const float* Xt = x + (size_t)(b + 8) * NFULL;

  f32x4 acc[4][4];
#pragma unroll
  for (int a = 0; a < 4; ++a)
#pragma unroll
    for (int bb = 0; bb < 4; ++bb) acc[a][bb] = (f32x4){0.f, 0.f, 0.f, 0.f};
  float rtp[2] = {0.f, 0.f}, rsp[2] = {0.f, 0.f};

  for (int s = 0; s < nst; ++s) {
    const int nb = n0 + s * 64;
    __syncthreads();                   // prev-stage reads done before overwrite
#pragma unroll
    for (int p = 0; p < 2; ++p) {
      const int row = r0 + 64 * p;
      const float* At = Xt + (size_t)row * NSP + nb + q * 16;
      const float* Bs = Xs + (size_t)row * NSP + nb + q * 16;
      f32x4 av[4], bv[4];
#pragma unroll
      for (int i = 0; i < 4; ++i) av[i] = *(const f32x4*)(At + i * 4);
#pragma unroll
      for (int i = 0; i < 4; ++i) bv[i] = *(const f32x4*)(Bs + i * 4);
#pragma unroll
      for (int i = 0; i < 4; ++i) {
        rtp[p] += (av[i][0] + av[i][1]) + (av[i][2] + av[i][3]);
        rsp[p] += (bv[i][0] + bv[i][1]) + (bv[i][2] + bv[i][3]);
      }
      u32x4 h0, l0, h1, l1;
#pragma unroll
      for (int i = 0; i < 2; ++i) {
        uint2 r1 = packpair(av[i][0], av[i][1]);
        h0[2 * i] = r1.x; l0[2 * i] = r1.y;
        uint2 r2 = packpair(av[i][2], av[i][3]);
        h0[2 * i + 1] = r2.x; l0[2 * i + 1] = r2.y;
        uint2 r3 = packpair(av[2 + i][0], av[2 + i][1]);
        h1[2 * i] = r3.x; l1[2 * i] = r3.y;
        uint2 r4 = packpair(av[2 + i][2], av[2 + i][3]);
        h1[2 * i + 1] = r4.x; l1[2 * i + 1] = r4.y;
      }
      {
        int base = row * 128 + q * 32;
        int sw = (row & 7) << 4;
        *(u32x4*)((char*)Ahi + ((base) ^ sw)) = h0;
        *(u32x4*)((char*)Ahi + ((base + 16) ^ sw)) = h1;
        *(u32x4*)((char*)Alo + ((base) ^ sw)) = l0;
        *(u32x4*)((char*)Alo + ((base + 16) ^ sw)) = l1;
      }
#pragma unroll
      for (int i = 0; i < 2; ++i) {
        uint2 r1 = packpair(bv[i][0], bv[i][1]);
        h0[2 * i] = r1.x; l0[2 * i] = r1.y;
        uint2 r2 = packpair(bv[i][2], bv[i][3]);
        h0[2 * i + 1] = r2.x; l0[2 * i + 1] = r2.y;
        uint2 r3 = packpair(bv[2 + i][0], bv[2 + i][1]);
        h1[2 * i] = r3.x; l1[2 * i] = r3.y;
        uint2 r4 = packpair(bv[2 + i][2], bv[2 + i][3]);
        h1[2 * i + 1] = r4.x; l1[2 * i + 1] = r4.y;
      }
      {
        int base = row * 128 + q * 32;
        int sw = (row & 7) << 4;
        *(u32x4*)((char*)Bhi + ((base) ^ sw)) = h0;
        *(u32x4*)((char*)Bhi + ((base + 16) ^ sw)) = h1;
        *(u32x4*)((char*)Blo + ((base) ^ sw)) = l0;
        *(u32x4*)((char*)Blo + ((base + 16) ^ sw)) = l1;
      }
    }
    __syncthreads();
#pragma unroll
    for (int kk = 0; kk < 2; ++kk) {
      s16x8 ah[4], al[4], bh[4], bl[4];
#pragma unroll
      for (int a = 0; a < 4; ++a) {
        int row = wr * 64 + a * 16 + lr;
        int off = (row * 128 + kk * 64 + lg * 16) ^ ((row & 7) << 4);
        ah[a] = *(const s16x8*)((char*)Ahi + off);
        al[a] = *(const s16x8*)((char*)Alo + off);
      }
#pragma unroll
      for (int bb = 0; bb < 4; ++bb) {
        int row = wc * 64 + bb * 16 + lr;
        int off = (row * 128 + kk * 64 + lg * 16) ^ ((row & 7) << 4);
        bh[bb] = *(const s16x8*)((char*)Bhi + off);
        bl[bb] = *(const s16x8*)((char*)Blo + off);
      }
#pragma unroll
      for (int a = 0; a < 4; ++a)
#pragma unroll
        for (int bb = 0; bb < 4; ++bb) {
          acc[a][bb] = __builtin_amdgcn_mfma_f32_16x16x32_bf16(ah[a], bh[bb], acc[a][bb], 0, 0, 0);
          acc[a][bb] = __builtin_amdgcn_mfma_f32_16x16x32_bf16(ah[a], bl[bb], acc[a][bb], 0, 0, 0);
          acc[a][bb] = __builtin_amdgcn_mfma_f32_16x16x32_bf16(al[a], bh[bb], acc[a][bb], 0, 0, 0);
        }
    }
  }

  // row-sum reduce over the 4 n-quarters (lanes l^1, l^2 share a row)
#pragma unroll
  for (int p = 0; p < 2; ++p) {
    float vt = rtp[p];
    vt += __shfl_xor(vt, 1);
    vt += __shfl_xor(vt, 2);
    float vs = rsp[p];
    vs += __shfl_xor(vs, 1);
    vs += __shfl_xor(vs, 2);
    if (q == 0) {
      int row = r0 + 64 * p;
      if (mode == 0) {
        rtpart[((size_t)chunk * 8 + b) * CC + row] = vt;
        rspart[((size_t)chunk * 8 + b) * CC + row] = vs;
      } else {
        atomicAdd(&rt[b * CC + row], vt);
        atomicAdd(&rs[b * CC + row], vs);
      }
    }
  }

  const int rquad = lg << 2;
  if (mode == 0) {
    float* Mp = Mdst + ((size_t)chunk * 8 + b) * (CC * CC);
#pragma unroll
    for (int a = 0; a < 4; ++a)
#pragma unroll
      for (int bb = 0; bb < 4; ++bb)
#pragma unroll
        for (int r = 0; r < 4; ++r) {
          int i = wr * 64 + a * 16 + rquad + r;
          int j = wc * 64 + bb * 16 + lr;
          Mp[i * CC + j] = acc[a][bb][r];
        }
  } else {
    float* Mp = Mdst + (size_t)b * (CC * CC);
#pragma unroll
    for (int a = 0; a < 4; ++a)
#pragma unroll
      for (int bb = 0; bb < 4; ++bb)
#pragma unroll
        for (int r = 0; r < 4; ++r) {
          int i = wr * 64 + a * 16 + rquad + r;
          int j = wc * 64 + bb * 16 + lr;
          atomicAdd(&Mp[i * CC + j], acc[a][bb][r]);
        }
  }
}

// Sum partials, vectorized. Blocks [0,128): M. Block 128: rt. Block 129: rs.
__global__ __launch_bounds__(256) void k1_reduce(const float* __restrict__ Mpart,
    const float* __restrict__ rspart, const float* __restrict__ rtpart,
    float* __restrict__ M, float* __restrict__ rs, float* __restrict__ rt,
    int NB) {
  const int t = threadIdx.x;
  if (blockIdx.x < 128) {
    const int i4 = blockIdx.x * 256 + t;     // < 32768
    const int b = i4 >> 12;
    const int e = (i4 & 4095) * 4;
    f32x4 s = (f32x4){0.f, 0.f, 0.f, 0.f};
    for (int c = 0; c < NB; ++c) {
      f32x4 v = *(const f32x4*)(Mpart + ((size_t)c * 8 + b) * (CC * CC) + e);
      s += v;
    }
    *(f32x4*)(M + (size_t)b * CC * CC + e) = s;
  } else if (blockIdx.x == 128) {
    const int e = t * 4;                      // < 1024
    f32x4 s = (f32x4){0.f, 0.f, 0.f, 0.f};
    for (int c = 0; c < NB; ++c) s += *(const f32x4*)(rtpart + (size_t)c * 1024 + e);
    *(f32x4*)(rt + e) = s;
  } else {
    const int e = t * 4;
    f32x4 s = (f32x4){0.f, 0.f, 0.f, 0.f};
    for (int c = 0; c < NB; ++c) s += *(const f32x4*)(rspart + (size_t)c * 1024 + e);
    *(f32x4*)(rs + e) = s;
  }
}

// ---------------------------------------------------------------------------
// K2ab fused: T1=Wq*M, T2=Wq*M^T, us/ut, G + softmax (st & ts).
// grid (16 c-groups of 8 rows, 8 b). Cols strided: lane L owns {L+32j}.
// ---------------------------------------------------------------------------
__global__ __launch_bounds__(256) void k2ab(const float* __restrict__ M,
    const float* __restrict__ qw, const float* __restrict__ kw,
    const float* __restrict__ qb, const float* __restrict__ kb,
    const float* __restrict__ rs, const float* __restrict__ rt,
    float* __restrict__ Ast, float* __restrict__ Ats) {
  const int b = blockIdx.y;
  const int c0 = blockIdx.x * 8;
  __shared__ float Big[128][132];      // M, later Wk (132: 16B-aligned rows)
  __shared__ float Wq[8][128];
  __shared__ float T12[2][8][128];
  __shared__ float uvv[2][8];
  __shared__ float wv2[2][128];
  const int t = threadIdx.x;
  const float* Mb = M + (size_t)b * CC * CC;
#pragma unroll
  for (int p = 0; p < 16; ++p) {
    int f = p * 256 + t;
    int row = f >> 5, c4 = (f & 31) * 4;
    *(f32x4*)&Big[row][c4] = *(const f32x4*)(Mb + row * CC + c4);
  }
  { int row = t >> 5, c4 = (t & 31) * 4;
    *(f32x4*)&Wq[row][c4] = *(const f32x4*)(qw + (c0 + row) * CC + c4); }
  __syncthreads();
  if (t < 16) {
    int c = t & 7;
    const float* r = ((t < 8) ? rs : rt) + b * CC;
    float s = 0.f;
    for (int i = 0; i < CC; ++i) s += Wq[c][i] * r[i];
    uvv[(t < 8) ? 1 : 0][c] = s;       // us->[1], ut->[0]
  }
  const int tr = t >> 5;               // row 0..7
  const int L = t & 31;                // col lane
  {
    float a1[4] = {0.f, 0.f, 0.f, 0.f}, a2[4] = {0.f, 0.f, 0.f, 0.f};
    for (int i = 0; i < CC; ++i) {
      float wq = Wq[tr][i];
#pragma unroll
      for (int j = 0; j < 4; ++j) a1[j] += wq * Big[i][L + 32 * j];
    }
    for (int i4 = 0; i4 < 32; ++i4) {
      f32x4 wq4 = *(const f32x4*)&Wq[tr][i4 * 4];
#pragma unroll
      for (int j = 0; j < 4; ++j) {
        f32x4 m4 = *(const f32x4*)&Big[L + 32 * j][i4 * 4];
        a2[j] += wq4[0]*m4[0] + wq4[1]*m4[1] + wq4[2]*m4[2] + wq4[3]*m4[3];
      }
    }
#pragma unroll
    for (int j = 0; j < 4; ++j) {
      T12[0][tr][L + 32 * j] = a1[j];
      T12[1][tr][L + 32 * j] = a2[j];
    }
  }
  __syncthreads();
  // overwrite Big with Wk
#pragma unroll
  for (int p = 0; p < 16; ++p) {
    int f = p * 256 + t;
    int row = f >> 5, c4 = (f & 31) * 4;
    *(f32x4*)&Big[row][c4] = *(const f32x4*)(kw + row * CC + c4);
  }
  __syncthreads();
  {
    int d = t & 127, wh = t >> 7;      // 0: rs, 1: rt
    const float* r = (wh ? rt : rs) + b * CC;
    float s = 0.f;
    for (int i4 = 0; i4 < 32; ++i4) {
      f32x4 w4 = *(const f32x4*)&Big[d][i4 * 4];
      s += w4[0]*r[i4*4] + w4[1]*r[i4*4+1] + w4[2]*r[i4*4+2] + w4[3]*r[i4*4+3];
    }
    wv2[wh][d] = s;
  }
  __syncthreads();
  const int c = c0 + tr;
  const float bqc = qb[c];
#pragma unroll 1
  for (int which = 0; which < 2; ++which) {
    float g[4];
#pragma unroll
    for (int j = 0; j < 4; ++j) {
      int d = L + 32 * j;
      g[j] = uvv[which][tr] * kb[d] + bqc * wv2[which][d] + 16384.f * bqc * kb[d];
    }
    for (int j4 = 0; j4 < 32; ++j4) {
      f32x4 tv4 = *(const f32x4*)&T12[which][tr][j4 * 4];
#pragma unroll
      for (int j = 0; j < 4; ++j) {
        f32x4 w4 = *(const f32x4*)&Big[L + 32 * j][j4 * 4];
        g[j] += tv4[0]*w4[0] + tv4[1]*w4[1] + tv4[2]*w4[2] + tv4[3]*w4[3];
      }
    }
    float m = fmaxf(fmaxf(g[0], g[1]), fmaxf(g[2], g[3]));
#pragma unroll
    for (int off = 1; off < 32; off <<= 1) m = fmaxf(m, __shfl_xor(m, off));
    float s = 0.f;
#pragma unroll
    for (int j = 0; j < 4; ++j) { g[j] = expf(g[j] - m); s += g[j]; }
#pragma unroll
    for (int off = 1; off < 32; off <<= 1) s += __shfl_xor(s, off);
    const float inv = 1.f / s;
    float* A = (which ? Ats : Ast) + (size_t)b * CC * CC + (size_t)c * CC;
#pragma unroll
    for (int j = 0; j < 4; ++j) A[L + 32 * j] = g[j] * inv;
  }
}

// ---------------------------------------------------------------------------
// K2cd fused: L = Ast*Ats^T, softmax -> Att, P' = Att*Wv + I (bf16), c0.
// grid (16 c-groups of 8 rows, 8 b).
// ---------------------------------------------------------------------------
__global__ __launch_bounds__(256) void k2cd(const float* __restrict__ Ast,
    const float* __restrict__ Ats, const float* __restrict__ vw,
    const float* __restrict__ vb, unsigned short* __restrict__ Pbf,
    float* __restrict__ c0v) {
  const int b = blockIdx.y;
  const int c0 = blockIdx.x * 8;
  __shared__ float Big[128][132];      // Ats, later Wv[d][i]
  __shared__ float Tl[8][128];
  __shared__ float Al[8][128];
  const int t = threadIdx.x;
  const float* Bb = Ats + (size_t)b * CC * CC;
  const float* Tb = Ast + (size_t)b * CC * CC;
#pragma unroll
  for (int p = 0; p < 16; ++p) {
    int f = p * 256 + t;
    int row = f >> 5, c4 = (f & 31) * 4;
    *(f32x4*)&Big[row][c4] = *(const f32x4*)(Bb + row * CC + c4);
  }
  { int row = t >> 5, c4 = (t & 31) * 4;
    *(f32x4*)&Tl[row][c4] = *(const f32x4*)(Tb + (c0 + row) * CC + c4); }
  __syncthreads();
  const int tr = t >> 5;
  const int L = t & 31;
  {
    float g[4] = {0.f, 0.f, 0.f, 0.f};
    for (int e4 = 0; e4 < 32; ++e4) {
      f32x4 tv4 = *(const f32x4*)&Tl[tr][e4 * 4];
#pragma unroll
      for (int j = 0; j < 4; ++j) {
        f32x4 a4 = *(const f32x4*)&Big[L + 32 * j][e4 * 4];
        g[j] += tv4[0]*a4[0] + tv4[1]*a4[1] + tv4[2]*a4[2] + tv4[3]*a4[3];
      }
    }
    float m = fmaxf(fmaxf(g[0], g[1]), fmaxf(g[2], g[3]));
#pragma unroll
    for (int off = 1; off < 32; off <<= 1) m = fmaxf(m, __shfl_xor(m, off));
    float s = 0.f;
#pragma unroll
    for (int j = 0; j < 4; ++j) { g[j] = expf(g[j] - m); s += g[j]; }
#pragma unroll
    for (int off = 1; off < 32; off <<= 1) s += __shfl_xor(s, off);
    const float inv = 1.f / s;
#pragma unroll
    for (int j = 0; j < 4; ++j) Al[tr][L + 32 * j] = g[j] * inv;
  }
  __syncthreads();
  // overwrite Big with Wv[d][i]
#pragma unroll
  for (int p = 0; p < 16; ++p) {
    int f = p * 256 + t;
    int row = f >> 5, c4 = (f & 31) * 4;
    *(f32x4*)&Big[row][c4] = *(const f32x4*)(vw + row * CC + c4);
  }
  __syncthreads();
  float p4[4] = {0.f, 0.f, 0.f, 0.f};
  for (int d = 0; d < CC; ++d) {
    float av = Al[tr][d];
#pragma unroll
    for (int j = 0; j < 4; ++j) p4[j] += av * Big[d][L + 32 * j];
  }
  float csum = 0.f;
#pragma unroll
  for (int j = 0; j < 4; ++j) csum += Al[tr][L + 32 * j] * vb[L + 32 * j];
#pragma unroll
  for (int off = 1; off < 32; off <<= 1) csum += __shfl_xor(csum, off);
  const int c = c0 + tr;
  if ((c & 31) == L) p4[c >> 5] += 1.0f;      // P' = P + I (residual folded in)
  unsigned short* Pp = Pbf + (size_t)b * CC * CC + (size_t)c * CC;
#pragma unroll
  for (int j = 0; j < 4; ++j) Pp[L + 32 * j] = (unsigned short)bf16rne(p4[j]);
  if (L == 0) c0v[b * CC + c] = csum;
}

// ---------------------------------------------------------------------------
// K3 (MFMA): out[c][n] = sum_e P'[c][e]*x[e][n] + c0[c]  (identity in P').
// 256-n tile per block staged ONCE to LDS (transposed bf16, swizzled);
// P' fragments hoisted to registers per c-half and reused across 4 subtiles.
// Output via nontemporal stores. grid (64 n-tiles, 16 images), 4 waves.
// ---------------------------------------------------------------------------
__global__ __launch_bounds__(256, 2) void k3_mfma(const float* __restrict__ x,
    const unsigned short* __restrict__ Pbf, const float* __restrict__ c0v,
    float* __restrict__ out) {
  const int im = blockIdx.y;
  const int pb = im & 7;
  const int n0 = blockIdx.x * 256;
  const float* X = x + (size_t)im * NFULL;
  float* O = out + (size_t)im * NFULL;
  __shared__ unsigned short XT[256 * 128];   // swizzled: byte ^ (((n>>2)&15)<<4)
  __shared__ float c0l[128];
  const int t = threadIdx.x;
  if (t < 128) c0l[t] = c0v[pb * CC + t];
#pragma unroll
  for (int p = 0; p < 16; ++p) {
    int d0 = 2 * (t >> 4) + 32 * (p & 3);
    int n4 = (t & 15) * 4 + 64 * (p >> 2);
    f32x4 x0 = *(const f32x4*)(X + (size_t)d0 * NSP + n0 + n4);
    f32x4 x1 = *(const f32x4*)(X + (size_t)(d0 + 1) * NSP + n0 + n4);
#pragma unroll
    for (int i = 0; i < 4; ++i) {
      int n = n4 + i;
      __hip_bfloat162 h2 = __float22bfloat162_rn(make_float2(x0[i], x1[i]));
      unsigned pk = *reinterpret_cast<unsigned*>(&h2);
      int off = (n * 256 + d0 * 2) ^ (((n >> 2) & 15) << 4);
      *(unsigned*)((char*)XT + off) = pk;
    }
  }
  __syncthreads();

  const int w = t >> 6, l = t & 63;
  const int ln = l & 15, lg = l >> 4;
#pragma unroll
  for (int h = 0; h < 2; ++h) {
    const unsigned short* Pg = Pbf + (size_t)pb * (CC * CC)
                             + (size_t)(h * 64 + ln) * CC + lg * 8;
    s16x8 Af[4][4];
#pragma unroll
    for (int a = 0; a < 4; ++a)
#pragma unroll
      for (int kk = 0; kk < 4; ++kk)
        Af[a][kk] = *(const s16x8*)(Pg + a * 16 * CC + kk * 32);
#pragma unroll
    for (int sub = 0; sub < 4; ++sub) {
      int row = sub * 64 + w * 16 + ln;
      int sw = ((row >> 2) & 15) << 4;
      s16x8 bf[4];
#pragma unroll
      for (int kk = 0; kk < 4; ++kk)
        bf[kk] = *(const s16x8*)((char*)XT + ((row * 256 + kk * 64 + lg * 16) ^ sw));
      f32x4 acc[4];
#pragma unroll
      for (int a = 0; a < 4; ++a) acc[a] = (f32x4){0.f, 0.f, 0.f, 0.f};
#pragma unroll
      for (int kk = 0; kk < 4; ++kk)
#pragma unroll
        for (int a = 0; a < 4; ++a)
          acc[a] = __builtin_amdgcn_mfma_f32_16x16x32_bf16(Af[a][kk], bf[kk], acc[a], 0, 0, 0);
      int n = n0 + sub * 64 + w * 16 + ln;
#pragma unroll
      for (int a = 0; a < 4; ++a)
#pragma unroll
        for (int r = 0; r < 4; ++r) {
          int c = h * 64 + a * 16 + lg * 4 + r;
          __builtin_nontemporal_store(acc[a][r] + c0l[c], O + (size_t)c * NSP + n);
        }
    }
  }
}

// ---------------------------------------------------------------------------
extern "C" void kernel_launch(void* const* d_in, const int* in_sizes, int n_in,
                              void* d_out, int out_size, void* d_ws, size_t ws_size,
                              hipStream_t stream) {
  (void)in_sizes; (void)n_in; (void)out_size;
  const float* x  = (const float*)d_in[0];
  const float* qw = (const float*)d_in[1];
  const float* qb = (const float*)d_in[2];
  const float* kw = (const float*)d_in[3];
  const float* kb = (const float*)d_in[4];
  const float* vw = (const float*)d_in[5];
  const float* vb = (const float*)d_in[6];
  float* out = (float*)d_out;
  float* ws = (float*)d_ws;
  float* M   = ws;                       // 8*128*128  (M, rs, rt contiguous)
  float* rs  = M + 131072;               // 8*128
  float* rt  = rs + 1024;
  float* AST = rt + 1024;                // 8*128*128
  float* ATS = AST + 131072;
  unsigned short* Pbf = (unsigned short*)(ATS + 131072);  // 8*128*128 bf16
  float* c0v = ATS + 131072 + 65536;
  float* Mpart = c0v + 1024;
  const size_t base_floats = (size_t)(Mpart - ws);

  int NB, mode;
  if (ws_size >= (base_floats + (size_t)64 * (131072 + 2048)) * 4) { NB = 64; mode = 0; }
  else if (ws_size >= (base_floats + (size_t)32 * (131072 + 2048)) * 4) { NB = 32; mode = 0; }
  else { NB = 32; mode = 1; }
  const int nst = (16384 / NB) / 64;     // 64-n stages per chunk
  float* rtpart = Mpart + (size_t)NB * 131072;   // NB*8*128
  float* rspart = rtpart + (size_t)NB * 1024;    // NB*8*128

  if (mode == 1) zerok<<<(133120 + 255) / 256, 256, 0, stream>>>(M, 133120);
  k1_mfma<<<dim3(NB, 8), 256, 0, stream>>>(x, mode ? M : Mpart, rs, rt,
                                           rspart, rtpart, nst, mode);
  if (mode == 0)
    k1_reduce<<<130, 256, 0, stream>>>(Mpart, rspart, rtpart, M, rs, rt, NB);
  k2ab<<<dim3(16, 8), 256, 0, stream>>>(M, qw, kw, qb, kb, rs, rt, AST, ATS);
  k2cd<<<dim3(16, 8), 256, 0, stream>>>(AST, ATS, vw, vb, Pbf, c0v);
  k3_mfma<<<dim3(64, 16), 256, 0, stream>>>(x, Pbf, c0v, out);
}